// Round 6
// baseline (271.536 us; speedup 1.0000x reference)
//
#include <hip/hip_runtime.h>
#include <hip/hip_bf16.h>
#include <math.h>

// Problem constants
constexpr int NN = 50000;   // nodes
constexpr int NE = 800000;  // edges (without self loops)
constexpr int ET = NE + NN; // edges + self loops
constexpr int FH = 128;     // HEADS*HID = feature width (also IN_CH)
constexpr int NHEAD = 4;
constexpr int NG = 64;      // graphs
constexpr int OC = 10;      // out channels

// Multisplit CSR build: buckets of 256 nodes (bucket = dst >> 8).
// Zero global atomics anywhere (global atomics write through to the memory
// side, ~32B each -- round-1 counters).
constexpr int NBK = (NN + 255) >> 8;   // 196 buckets
constexpr int EPB = 4000;              // edges per hist/scatter block
constexpr int HBLK = NE / EPB;         // 200 blocks

// W^T pack: [128 n][136 k] ushort, padded to 136 for LDS bank stagger
constexpr int WKP = 136;
constexpr int WPLANE = 128 * WKP;   // ushorts per plane (hi or lo)

// A-tile for the fused agg+gemm kernel: 256 rows x 136 ushort (16B-aligned
// stride; per-8-lane bank pattern conflict-free for b128 reads)
constexpr int AKP = 136;

constexpr int GEMM1_GRID = (NN + 255) / 256;  // 196 blocks x 1024 thr (16 waves)

typedef __attribute__((ext_vector_type(8))) short short8;
typedef __attribute__((ext_vector_type(4))) float f32x4;

__device__ inline ushort f2bf_bits(float f) {
    union { __hip_bfloat16 h; ushort u; } c;
    c.h = __float2bfloat16(f);
    return c.u;
}

// ---------------------------------------------------------------------------
// MFMA GEMM + attention epilogue (per-wave; wave/row0 set by caller).
// C/D layout: col=lane&15, row=quad*4+reg.
// ---------------------------------------------------------------------------
#define GEMM_EPILOGUE()                                                          \
    float as_[8], ad_[8];                                                        \
    _Pragma("unroll")                                                            \
    for (int t = 0; t < 8; ++t) {                                                \
        as_[t] = att_s[t * 16 + l16];                                            \
        ad_[t] = att_d[t * 16 + l16];                                            \
    }                                                                            \
    float hs[4][4], hd[4][4];                                                    \
    _Pragma("unroll")                                                            \
    for (int r = 0; r < 4; ++r) {                                                \
        int grow = row0 + quad * 4 + r;                                          \
        bool okr = (grow < NN);                                                  \
        _Pragma("unroll")                                                        \
        for (int h = 0; h < 4; ++h) {                                            \
            hs[r][h] = acc[2*h][r] * as_[2*h] + acc[2*h+1][r] * as_[2*h+1];      \
            hd[r][h] = acc[2*h][r] * ad_[2*h] + acc[2*h+1][r] * ad_[2*h+1];      \
        }                                                                        \
        if (okr) {                                                               \
            _Pragma("unroll")                                                    \
            for (int t = 0; t < 8; ++t)                                          \
                Hb[(size_t)grow * FH + t * 16 + l16] = __float2bfloat16(acc[t][r]); \
        }                                                                        \
    }                                                                            \
    _Pragma("unroll")                                                            \
    for (int o = 1; o < 16; o <<= 1) {                                           \
        _Pragma("unroll")                                                        \
        for (int r = 0; r < 4; ++r)                                              \
            _Pragma("unroll")                                                    \
            for (int h = 0; h < 4; ++h) {                                        \
                hs[r][h] += __shfl_xor(hs[r][h], o);                             \
                hd[r][h] += __shfl_xor(hd[r][h], o);                             \
            }                                                                    \
    }                                                                            \
    if (l16 == 0) {                                                              \
        _Pragma("unroll")                                                        \
        for (int r = 0; r < 4; ++r) {                                            \
            int grow = row0 + quad * 4 + r;                                      \
            if (grow < NN) {                                                     \
                *(float4*)&a_src[grow * NHEAD] = make_float4(hs[r][0], hs[r][1], hs[r][2], hs[r][3]); \
                *(float4*)&a_dst[grow * NHEAD] = make_float4(hd[r][0], hd[r][1], hd[r][2], hd[r][3]); \
            }                                                                    \
        }                                                                        \
    }

// ---------------------------------------------------------------------------
// Fused dispatch (1024 threads):
//  blocks [0, GEMM1_GRID): layer-1 GEMM; converts W1 f32 -> split-bf16 LDS
//    in-kernel.
//  blocks [GEMM1_GRID, +HBLK): per-block bucket histogram (LDS atomics only,
//    plain stores) + side job: first 64 of them pack W2 into wt (read only
//    by the later fused agg+gemm dispatch).
// ---------------------------------------------------------------------------
__global__ __launch_bounds__(1024) void fused_gemm_hist_kernel(
    const int* __restrict__ ei, int* __restrict__ blockHist,
    const float* __restrict__ A, const float* __restrict__ W1,
    const float* __restrict__ W2, ushort* __restrict__ wt,
    const float* __restrict__ att_s, const float* __restrict__ att_d,
    __hip_bfloat16* __restrict__ Hb, float* __restrict__ a_src, float* __restrict__ a_dst)
{
    __shared__ __align__(16) ushort Wlds[2 * WPLANE];
    const int tid = threadIdx.x;

    if (blockIdx.x >= GEMM1_GRID) {
        const int blk = blockIdx.x - GEMM1_GRID;
        int* hist = (int*)Wlds;
        if (tid < NBK) hist[tid] = 0;
        __syncthreads();
        const int e0 = blk * EPB;
        if (tid < EPB / 4) {
            int4 d4 = *(const int4*)(ei + NE + e0 + 4 * tid);
            atomicAdd(&hist[d4.x >> 8], 1);
            atomicAdd(&hist[d4.y >> 8], 1);
            atomicAdd(&hist[d4.z >> 8], 1);
            atomicAdd(&hist[d4.w >> 8], 1);
        }
        // side job: pack W2 (split precision) for the fused agg+gemm dispatch
        if (blk < 64 && tid < 256) {
            int idx = blk * 256 + tid;          // 0..16383
            int k = idx >> 7, n = idx & 127;
            float f = W2[idx];
            ushort hb = f2bf_bits(f);
            union { ushort u; __hip_bfloat16 h; } c; c.u = hb;
            float lo = f - __bfloat162float(c.h);
            wt[n * WKP + k] = hb;
            wt[WPLANE + n * WKP + k] = f2bf_bits(lo);
        }
        __syncthreads();
        if (tid < NBK) blockHist[tid * HBLK + blk] = hist[tid];
        return;
    }

    // ---- layer-1 GEMM (f32 input, split precision), 16 waves ----
    for (int i = tid; i < FH * 128; i += 1024) {
        int k = i >> 7, n = i & 127;
        float f = W1[i];                        // W1[k*128+n]
        ushort hb = f2bf_bits(f);
        union { ushort u; __hip_bfloat16 h; } c; c.u = hb;
        float lo = f - __bfloat162float(c.h);
        Wlds[n * WKP + k] = hb;
        Wlds[WPLANE + n * WKP + k] = f2bf_bits(lo);
    }
    __syncthreads();

    const int wave = tid >> 6;         // 0..15
    const int lane = tid & 63;
    const int quad = lane >> 4;
    const int l16 = lane & 15;
    const int row0 = blockIdx.x * 256 + wave * 16;

    f32x4 acc[8];
#pragma unroll
    for (int t = 0; t < 8; ++t) acc[t] = (f32x4){0.f, 0.f, 0.f, 0.f};

    int arow = row0 + l16; if (arow >= NN) arow = NN - 1;
    const float* ap = A + (size_t)arow * FH + quad * 8;

#pragma unroll
    for (int kc = 0; kc < 4; ++kc) {
        float4 x0 = *(const float4*)(ap + kc * 32);
        float4 x1 = *(const float4*)(ap + kc * 32 + 4);
        float av[8] = {x0.x, x0.y, x0.z, x0.w, x1.x, x1.y, x1.z, x1.w};
        short8 ah, al;
#pragma unroll
        for (int j = 0; j < 8; ++j) {
            ushort hb = f2bf_bits(av[j]);
            union { ushort u; __hip_bfloat16 h; } c; c.u = hb;
            float lo = av[j] - __bfloat162float(c.h);
            ah[j] = (short)hb;
            al[j] = (short)f2bf_bits(lo);
        }
        const int kof = kc * 32 + quad * 8;
#pragma unroll
        for (int t = 0; t < 8; ++t) {
            const ushort* wp = &Wlds[(t * 16 + l16) * WKP + kof];
            short8 wh = *(const short8*)wp;
            short8 wl = *(const short8*)(wp + WPLANE);
            acc[t] = __builtin_amdgcn_mfma_f32_16x16x32_bf16(ah, wh, acc[t], 0, 0, 0);
            acc[t] = __builtin_amdgcn_mfma_f32_16x16x32_bf16(al, wh, acc[t], 0, 0, 0);
            acc[t] = __builtin_amdgcn_mfma_f32_16x16x32_bf16(ah, wl, acc[t], 0, 0, 0);
        }
    }
    GEMM_EPILOGUE()
}

// ---------------------------------------------------------------------------
// Merged scan (unchanged from round 4/5).
// ---------------------------------------------------------------------------
__global__ __launch_bounds__(256) void scanAB_kernel(const int* __restrict__ bh,
                                                     int* __restrict__ bstart,
                                                     int* __restrict__ ebase,
                                                     int* __restrict__ offs) {
    __shared__ int sd[256];
    __shared__ int bprefix;
    const int b = blockIdx.x, t = threadIdx.x;
    int v = 0;
    if (t < NBK) {
        const int* p = bh + t * HBLK;
        for (int i = 0; i < HBLK; ++i) v += p[i];
    }
    sd[t] = v; __syncthreads();
#pragma unroll
    for (int o = 1; o < 256; o <<= 1) {
        int u = (t >= o) ? sd[t - o] : 0;
        __syncthreads();
        sd[t] += u;
        __syncthreads();
    }
    if (t == b) bprefix = sd[t] - v;   // exclusive prefix for this bucket
    if (b == 0) {
        if (t < NBK) ebase[t] = sd[t] - v;
        if (t == NBK - 1) ebase[NBK] = sd[t];   // == NE
        if (t == 0) offs[NN] = ET;
    }
    __syncthreads();
    const int base = bprefix;
    __syncthreads();
    int c = (t < HBLK) ? bh[b * HBLK + t] : 0;
    sd[t] = c; __syncthreads();
#pragma unroll
    for (int o = 1; o < 256; o <<= 1) {
        int u = (t >= o) ? sd[t - o] : 0;
        __syncthreads();
        sd[t] += u;
        __syncthreads();
    }
    if (t < HBLK) bstart[b * HBLK + t] = base + sd[t] - c;
}

// ---------------------------------------------------------------------------
// Bucket scatter (unchanged).
// ---------------------------------------------------------------------------
__global__ __launch_bounds__(1024) void bucket_scatter_kernel(
    const int* __restrict__ ei, const int* __restrict__ bstart,
    int2* __restrict__ ebuf) {
    __shared__ int cur[NBK];
    const int tid = threadIdx.x;
    const int blk = blockIdx.x;
    for (int i = tid; i < NBK; i += 1024) cur[i] = bstart[i * HBLK + blk];
    __syncthreads();
    const int e0 = blk * EPB;
    if (tid < EPB / 4) {
        int4 d4 = *(const int4*)(ei + NE + e0 + 4 * tid);
        int4 s4 = *(const int4*)(ei + e0 + 4 * tid);
        int ds[4] = {d4.x, d4.y, d4.z, d4.w};
        int ss[4] = {s4.x, s4.y, s4.z, s4.w};
#pragma unroll
        for (int j = 0; j < 4; ++j) {
            int pos = atomicAdd(&cur[ds[j] >> 8], 1);
            ebuf[pos] = make_int2(ss[j], ds[j]);
        }
    }
}

// ---------------------------------------------------------------------------
// Per-bucket CSR finalize (unchanged).
// ---------------------------------------------------------------------------
__global__ __launch_bounds__(256) void bucket_csr_kernel(
    const int2* __restrict__ ebuf, const int* __restrict__ ebase,
    int* __restrict__ offs, int* __restrict__ csrc) {
    __shared__ int hist[256];
    __shared__ int sd[256];
    __shared__ int cur[256];
    const int b = blockIdx.x, t = threadIdx.x;
    const int lo = b << 8;
    int psz = NN - lo; if (psz > 256) psz = 256;
    const int e0 = ebase[b], e1 = ebase[b + 1];

    hist[t] = 0;
    __syncthreads();
    for (int k = e0 + t; k < e1; k += 256) {
        int2 e = ebuf[k];
        atomicAdd(&hist[e.y - lo], 1);
    }
    __syncthreads();
    const int d = hist[t];
    sd[t] = d; __syncthreads();
#pragma unroll
    for (int o = 1; o < 256; o <<= 1) {
        int u = (t >= o) ? sd[t - o] : 0;
        __syncthreads();
        sd[t] += u;
        __syncthreads();
    }
    const int ex = sd[t] - d;
    if (t < psz) {
        const int node = lo + t;
        const int o = e0 + ex + node;
        offs[node] = o;
        cur[t] = o;
        csrc[o + d] = node;             // self loop at end of the node's range
    }
    __syncthreads();
    for (int k = e0 + t; k < e1; k += 256) {
        int2 e = ebuf[k];
        int pos = atomicAdd(&cur[e.y - lo], 1);
        csrc[pos] = e.x;
    }
}

// ---------------------------------------------------------------------------
// FUSED agg1 + GEMM2 (196 blocks x 1024 threads).
// Phase A: one wave per node, 16 passes -> this block's 256 agg rows land in
//   an LDS A-tile (bf16, stride AKP=136 ushorts: 16B-aligned, conflict-free).
//   Consumer-only gather form (round-5 agg body), layer-1 inputs read-only.
// Phase B: GEMM2 (2-MFMA split-W) with A read from LDS; epilogue writes the
//   LAYER-2 buffers (hbuf2/asrc2/adst2 -- distinct from layer-1 inputs, since
//   other blocks may still be gathering layer-1 values).
// Eliminates the 12.8MB abuf write + 12.8MB read and one dispatch.
// ---------------------------------------------------------------------------
__global__ __launch_bounds__(1024) void fused_agg_gemm_kernel(
    const __hip_bfloat16* __restrict__ Hb1, const float* __restrict__ asrc,
    const float* __restrict__ adst, const int* __restrict__ offs,
    const int* __restrict__ csrc, const float* __restrict__ bias,
    const ushort* __restrict__ wt,
    const float* __restrict__ att_s, const float* __restrict__ att_d,
    __hip_bfloat16* __restrict__ Hb, float* __restrict__ a_src, float* __restrict__ a_dst)
{
    __shared__ __align__(16) ushort Wlds[2 * WPLANE];
    __shared__ __align__(16) ushort Atile[256 * AKP];
    const int tid = threadIdx.x;
    {
        const uint4* s = (const uint4*)wt;
        uint4* d = (uint4*)Wlds;
        for (int i = tid; i < 2 * WPLANE / 8; i += 1024) d[i] = s[i];
    }
    const int wave = tid >> 6;
    const int lane = tid & 63;
    const int es = lane >> 4;      // edge sub-slot 0..3
    const int fs = lane & 15;      // feature slot (8 feats each)
    const int hC = fs >> 2;        // head of these features
    const int f8 = fs * 8;

    // ---- Phase A: aggregate this block's 256 nodes into the LDS A-tile ----
    for (int j = 0; j < 16; ++j) {
        const int nl = j * 16 + wave;            // local row 0..255
        const int n = blockIdx.x * 256 + nl;
        if (n < NN) {
            const int beg = offs[n], end = offs[n + 1];
            const float adC = adst[n * NHEAD + hC];
            float dsum = 0.f;
            float acc[8];
#pragma unroll
            for (int i = 0; i < 8; ++i) acc[i] = 0.f;
            const int last = end - 1;
            const int n8 = (end - beg + 7) >> 3;
            for (int p = 0; p < n8; ++p) {
                const int eA = beg + 8 * p + es;
                const int eB = eA + 4;
                const bool vA = eA < end, vB = eB < end;
                const int sA = csrc[vA ? eA : last];
                const int sB = csrc[vB ? eB : last];
                float aA = asrc[sA * NHEAD + hC] + adC;
                float aB = asrc[sB * NHEAD + hC] + adC;
                aA = aA > 0.f ? aA : 0.2f * aA;
                aB = aB > 0.f ? aB : 0.2f * aB;
                const float wA = vA ? __expf(aA) : 0.f;
                const float wB = vB ? __expf(aB) : 0.f;
                dsum += wA + wB;
                union { uint4 u; __hip_bfloat162 b[4]; } cvA, cvB;
                cvA.u = *(const uint4*)&Hb1[(size_t)sA * FH + f8];
                cvB.u = *(const uint4*)&Hb1[(size_t)sB * FH + f8];
#pragma unroll
                for (int i = 0; i < 4; ++i) {
                    float2 hA = __bfloat1622float2(cvA.b[i]);
                    float2 hB2 = __bfloat1622float2(cvB.b[i]);
                    acc[2 * i]     = fmaf(wA, hA.x, acc[2 * i]);
                    acc[2 * i + 1] = fmaf(wA, hA.y, acc[2 * i + 1]);
                    acc[2 * i]     = fmaf(wB, hB2.x, acc[2 * i]);
                    acc[2 * i + 1] = fmaf(wB, hB2.y, acc[2 * i + 1]);
                }
            }
            dsum += __shfl_xor(dsum, 1);
            dsum += __shfl_xor(dsum, 2);
            dsum += __shfl_xor(dsum, 16);
            dsum += __shfl_xor(dsum, 32);
#pragma unroll
            for (int i = 0; i < 8; ++i) {
                acc[i] += __shfl_xor(acc[i], 16);
                acc[i] += __shfl_xor(acc[i], 32);
            }
            const float inv = 4.0f / dsum;
            if (es == 0) {
                union { ushort u8[8]; uint4 u; } pk;
#pragma unroll
                for (int i = 0; i < 8; ++i) {
                    float v = fmaxf(fmaf(acc[i], inv, bias[f8 + i]), 0.f);
                    pk.u8[i] = f2bf_bits(v);
                }
                *(uint4*)&Atile[nl * AKP + f8] = pk.u;
            }
        }
    }
    __syncthreads();

    // ---- Phase B: GEMM2 (bf16 2-MFMA), A from LDS ----
    const int quad = lane >> 4;
    const int l16 = lane & 15;
    const int row0 = blockIdx.x * 256 + wave * 16;

    f32x4 acc[8];
#pragma unroll
    for (int t = 0; t < 8; ++t) acc[t] = (f32x4){0.f, 0.f, 0.f, 0.f};

    const ushort* ap = &Atile[(wave * 16 + l16) * AKP + quad * 8];

#pragma unroll
    for (int kc = 0; kc < 4; ++kc) {
        short8 ah = *(const short8*)(ap + kc * 32);
        const int kof = kc * 32 + quad * 8;
#pragma unroll
        for (int t = 0; t < 8; ++t) {
            const ushort* wp = &Wlds[(t * 16 + l16) * WKP + kof];
            short8 wh = *(const short8*)wp;
            short8 wl = *(const short8*)(wp + WPLANE);
            acc[t] = __builtin_amdgcn_mfma_f32_16x16x32_bf16(ah, wh, acc[t], 0, 0, 0);
            acc[t] = __builtin_amdgcn_mfma_f32_16x16x32_bf16(ah, wl, acc[t], 0, 0, 0);
        }
    }
    GEMM_EPILOGUE()
}

// ---------------------------------------------------------------------------
// Per-node aggregation (layer 2), consumer-only straight-line form
// (round-5 structure), writes abuf for the pool.
// ---------------------------------------------------------------------------
__global__ __launch_bounds__(256) void gat_agg_kernel(
    const __hip_bfloat16* __restrict__ Hb, const float* __restrict__ asrc,
    const float* __restrict__ adst, const int* __restrict__ offs,
    const int* __restrict__ csrc, const float* __restrict__ bias,
    __hip_bfloat16* __restrict__ out)
{
    const int wid = threadIdx.x >> 6;
    const int lane = threadIdx.x & 63;
    const int n = blockIdx.x * 4 + wid;   // NN % 4 == 0, no bounds check

    const int beg = offs[n], end = offs[n + 1];
    const int es = lane >> 4;
    const int fs = lane & 15;
    const int hC = fs >> 2;
    const int f8 = fs * 8;
    const float adC = adst[n * NHEAD + hC];

    float dsum = 0.f;
    float acc[8];
#pragma unroll
    for (int i = 0; i < 8; ++i) acc[i] = 0.f;

    const int last = end - 1;
    const int n8 = (end - beg + 7) >> 3;
    for (int p = 0; p < n8; ++p) {
        const int eA = beg + 8 * p + es;
        const int eB = eA + 4;
        const bool vA = eA < end, vB = eB < end;
        const int sA = csrc[vA ? eA : last];
        const int sB = csrc[vB ? eB : last];
        float aA = asrc[sA * NHEAD + hC] + adC;
        float aB = asrc[sB * NHEAD + hC] + adC;
        aA = aA > 0.f ? aA : 0.2f * aA;
        aB = aB > 0.f ? aB : 0.2f * aB;
        const float wA = vA ? __expf(aA) : 0.f;
        const float wB = vB ? __expf(aB) : 0.f;
        dsum += wA + wB;
        union { uint4 u; __hip_bfloat162 b[4]; } cvA, cvB;
        cvA.u = *(const uint4*)&Hb[(size_t)sA * FH + f8];
        cvB.u = *(const uint4*)&Hb[(size_t)sB * FH + f8];
#pragma unroll
        for (int i = 0; i < 4; ++i) {
            float2 hA = __bfloat1622float2(cvA.b[i]);
            float2 hB2 = __bfloat1622float2(cvB.b[i]);
            acc[2 * i]     = fmaf(wA, hA.x, acc[2 * i]);
            acc[2 * i + 1] = fmaf(wA, hA.y, acc[2 * i + 1]);
            acc[2 * i]     = fmaf(wB, hB2.x, acc[2 * i]);
            acc[2 * i + 1] = fmaf(wB, hB2.y, acc[2 * i + 1]);
        }
    }
    dsum += __shfl_xor(dsum, 1);
    dsum += __shfl_xor(dsum, 2);
    dsum += __shfl_xor(dsum, 16);
    dsum += __shfl_xor(dsum, 32);
#pragma unroll
    for (int i = 0; i < 8; ++i) {
        acc[i] += __shfl_xor(acc[i], 16);
        acc[i] += __shfl_xor(acc[i], 32);
    }
    const float inv = 4.0f / dsum;
    if (es == 0) {
        union { ushort u8[8]; uint4 u; } pk;
#pragma unroll
        for (int i = 0; i < 8; ++i) {
            float v = fmaxf(fmaf(acc[i], inv, bias[f8 + i]), 0.f);
            pk.u8[i] = f2bf_bits(v);
        }
        *(uint4*)&out[(size_t)n * FH + f8] = pk.u;
    }
}

// ---------------------------------------------------------------------------
// Mean pool + final linear fused (unchanged).
// ---------------------------------------------------------------------------
__global__ __launch_bounds__(256) void pool_final_kernel(
    const __hip_bfloat16* __restrict__ X, const int* __restrict__ batch,
    const float* __restrict__ wl, const float* __restrict__ bl,
    float* __restrict__ out)
{
    const int g = blockIdx.x;
    const int t = threadIdx.x;
    int a = 0, b = NN;
    while (a < b) { int m = (a + b) >> 1; if (batch[m] < g) a = m + 1; else b = m; }
    const int gs = a;
    b = NN;
    while (a < b) { int m = (a + b) >> 1; if (batch[m] <= g) a = m + 1; else b = m; }
    const int ge = a;

    const int rg = t >> 4;
    const int l16 = t & 15;
    float acc[8];
#pragma unroll
    for (int i = 0; i < 8; ++i) acc[i] = 0.f;
    for (int r = gs + rg; r < ge; r += 16) {
        union { uint4 u; __hip_bfloat162 bb[4]; } cv;
        cv.u = *(const uint4*)&X[(size_t)r * FH + l16 * 8];
#pragma unroll
        for (int i = 0; i < 4; ++i) {
            float2 f = __bfloat1622float2(cv.bb[i]);
            acc[2 * i]     += f.x;
            acc[2 * i + 1] += f.y;
        }
    }
    __shared__ float red[16][128];
    __shared__ float pl[128];
#pragma unroll
    for (int i = 0; i < 8; ++i) red[rg][l16 * 8 + i] = acc[i];
    __syncthreads();
    if (t < 128) {
        float s = 0.f;
#pragma unroll
        for (int j = 0; j < 16; ++j) s += red[j][t];
        pl[t] = s;
    }
    __syncthreads();
    if (t < OC) {
        float invc = 1.0f / fmaxf((float)(ge - gs), 1.0f);
        float a2 = 0.f;
        for (int k = 0; k < FH; ++k)
            a2 = fmaf(pl[k], wl[k * OC + t], a2);
        out[g * OC + t] = a2 * invc + bl[t];
    }
}

// ---------------------------------------------------------------------------
extern "C" void kernel_launch(void* const* d_in, const int* in_sizes, int n_in,
                              void* d_out, int out_size, void* d_ws, size_t ws_size,
                              hipStream_t stream) {
    const float* x       = (const float*)d_in[0];
    const int*   ei      = (const int*)d_in[1];   // [2, NE]
    const int*   batch   = (const int*)d_in[2];
    const float* W1      = (const float*)d_in[3];
    const float* as1     = (const float*)d_in[4];
    const float* ad1     = (const float*)d_in[5];
    const float* b1      = (const float*)d_in[6];
    const float* W2      = (const float*)d_in[7];
    const float* as2     = (const float*)d_in[8];
    const float* ad2     = (const float*)d_in[9];
    const float* b2      = (const float*)d_in[10];
    const float* wlin    = (const float*)d_in[11];
    const float* blin    = (const float*)d_in[12];
    float* out = (float*)d_out;

    // workspace layout (everything fully rewritten each call -> no memset)
    __hip_bfloat16* hbuf1 = (__hip_bfloat16*)d_ws;         // NN*FH bf16 (layer1 gemm out)
    __hip_bfloat16* hbuf2 = hbuf1 + (size_t)NN * FH;       // NN*FH bf16 (layer2 gemm out)
    __hip_bfloat16* abuf  = hbuf2 + (size_t)NN * FH;       // NN*FH bf16 (layer2 agg out)
    float* asrc1 = (float*)(abuf + (size_t)NN * FH);       // NN*4
    float* adst1 = asrc1 + (size_t)NN * NHEAD;             // NN*4
    float* asrc2 = adst1 + (size_t)NN * NHEAD;             // NN*4
    float* adst2 = asrc2 + (size_t)NN * NHEAD;             // NN*4
    int* offs    = (int*)(adst2 + (size_t)NN * NHEAD);     // NN+1
    int* csrc    = offs + NN + 1;                          // ET
    int2* ebuf   = (int2*)(((uintptr_t)(csrc + ET) + 7) & ~(uintptr_t)7); // NE int2
    int* bh      = (int*)(ebuf + NE);         // NBK*HBLK
    int* bstart  = bh + NBK * HBLK;           // NBK*HBLK
    int* ebase   = bstart + NBK * HBLK;       // NBK+1
    ushort* wt   = (ushort*)(((uintptr_t)(ebase + NBK + 1) + 15) & ~(uintptr_t)15); // 2*WPLANE

    // 1. Fused: layer-1 GEMM (in-kernel W1 pack) + bucket hist + W2 pack
    fused_gemm_hist_kernel<<<GEMM1_GRID + HBLK, 1024, 0, stream>>>(
        ei, bh, x, W1, W2, wt, as1, ad1, hbuf1, asrc1, adst1);

    // 2-4. CSR build
    scanAB_kernel<<<NBK, 256, 0, stream>>>(bh, bstart, ebase, offs);
    bucket_scatter_kernel<<<HBLK, 1024, 0, stream>>>(ei, bstart, ebuf);
    bucket_csr_kernel<<<NBK, 256, 0, stream>>>(ebuf, ebase, offs, csrc);

    // 5. FUSED layer-1 aggregation + layer-2 GEMM (A-tile via LDS)
    fused_agg_gemm_kernel<<<GEMM1_GRID, 1024, 0, stream>>>(
        hbuf1, asrc1, adst1, offs, csrc, b1, wt, as2, ad2, hbuf2, asrc2, adst2);

    // 6. Layer 2 aggregation
    gat_agg_kernel<<<NN / 4, 256, 0, stream>>>(hbuf2, asrc2, adst2, offs, csrc, b2, abuf);

    // 7. Pool + final linear (fused)
    pool_final_kernel<<<NG, 256, 0, stream>>>(abuf, batch, wlin, blin, out);
}

// Round 7
// 248.492 us; speedup vs baseline: 1.0927x; 1.0927x over previous
//
#include <hip/hip_runtime.h>
#include <hip/hip_bf16.h>
#include <math.h>

// Problem constants
constexpr int NN = 50000;   // nodes
constexpr int NE = 800000;  // edges (without self loops)
constexpr int ET = NE + NN; // edges + self loops
constexpr int FH = 128;     // HEADS*HID = feature width (also IN_CH)
constexpr int NHEAD = 4;
constexpr int NG = 64;      // graphs
constexpr int OC = 10;      // out channels

// Multisplit CSR build: buckets of 256 nodes (bucket = dst >> 8).
// Zero global atomics anywhere (global atomics write through to the memory
// side, ~32B each -- round-1 counters).
constexpr int NBK = (NN + 255) >> 8;   // 196 buckets
constexpr int EPB = 4000;              // edges per hist/scatter block
constexpr int HBLK = NE / EPB;         // 200 blocks

// W^T pack: [128 n][136 k] ushort, padded to 136 for LDS bank stagger
constexpr int WKP = 136;
constexpr int WPLANE = 128 * WKP;   // ushorts per plane (hi or lo)

constexpr int GEMM1_GRID = (NN + 255) / 256;  // 196 blocks x 1024 thr (16 waves)
constexpr int GEMM2_GRID = (NN + 255) / 256;  // 196 blocks x 1024 thr (16 waves)

typedef __attribute__((ext_vector_type(8))) short short8;
typedef __attribute__((ext_vector_type(4))) float f32x4;

__device__ inline ushort f2bf_bits(float f) {
    union { __hip_bfloat16 h; ushort u; } c;
    c.h = __float2bfloat16(f);
    return c.u;
}

// ---------------------------------------------------------------------------
// MFMA GEMM + attention epilogue (per-wave; wave/row0 set by caller).
// C/D layout: col=lane&15, row=quad*4+reg.
// ---------------------------------------------------------------------------
#define GEMM_EPILOGUE()                                                          \
    float as_[8], ad_[8];                                                        \
    _Pragma("unroll")                                                            \
    for (int t = 0; t < 8; ++t) {                                                \
        as_[t] = att_s[t * 16 + l16];                                            \
        ad_[t] = att_d[t * 16 + l16];                                            \
    }                                                                            \
    float hs[4][4], hd[4][4];                                                    \
    _Pragma("unroll")                                                            \
    for (int r = 0; r < 4; ++r) {                                                \
        int grow = row0 + quad * 4 + r;                                          \
        bool okr = (grow < NN);                                                  \
        _Pragma("unroll")                                                        \
        for (int h = 0; h < 4; ++h) {                                            \
            hs[r][h] = acc[2*h][r] * as_[2*h] + acc[2*h+1][r] * as_[2*h+1];      \
            hd[r][h] = acc[2*h][r] * ad_[2*h] + acc[2*h+1][r] * ad_[2*h+1];      \
        }                                                                        \
        if (okr) {                                                               \
            _Pragma("unroll")                                                    \
            for (int t = 0; t < 8; ++t)                                          \
                Hb[(size_t)grow * FH + t * 16 + l16] = __float2bfloat16(acc[t][r]); \
        }                                                                        \
    }                                                                            \
    _Pragma("unroll")                                                            \
    for (int o = 1; o < 16; o <<= 1) {                                           \
        _Pragma("unroll")                                                        \
        for (int r = 0; r < 4; ++r)                                              \
            _Pragma("unroll")                                                    \
            for (int h = 0; h < 4; ++h) {                                        \
                hs[r][h] += __shfl_xor(hs[r][h], o);                             \
                hd[r][h] += __shfl_xor(hd[r][h], o);                             \
            }                                                                    \
    }                                                                            \
    if (l16 == 0) {                                                              \
        _Pragma("unroll")                                                        \
        for (int r = 0; r < 4; ++r) {                                            \
            int grow = row0 + quad * 4 + r;                                      \
            if (grow < NN) {                                                     \
                *(float4*)&a_src[grow * NHEAD] = make_float4(hs[r][0], hs[r][1], hs[r][2], hs[r][3]); \
                *(float4*)&a_dst[grow * NHEAD] = make_float4(hd[r][0], hd[r][1], hd[r][2], hd[r][3]); \
            }                                                                    \
        }                                                                        \
    }

// ---------------------------------------------------------------------------
// Fused dispatch (1024 threads):
//  blocks [0, GEMM1_GRID): layer-1 GEMM; converts W1 f32 -> split-bf16 LDS
//    in-kernel.
//  blocks [GEMM1_GRID, +HBLK): per-block bucket histogram (LDS atomics only,
//    plain stores) + side job: first 64 of them pack W2 into wt (read only
//    by the later gemm2 dispatch).
// ---------------------------------------------------------------------------
__global__ __launch_bounds__(1024) void fused_gemm_hist_kernel(
    const int* __restrict__ ei, int* __restrict__ blockHist,
    const float* __restrict__ A, const float* __restrict__ W1,
    const float* __restrict__ W2, ushort* __restrict__ wt,
    const float* __restrict__ att_s, const float* __restrict__ att_d,
    __hip_bfloat16* __restrict__ Hb, float* __restrict__ a_src, float* __restrict__ a_dst)
{
    __shared__ __align__(16) ushort Wlds[2 * WPLANE];
    const int tid = threadIdx.x;

    if (blockIdx.x >= GEMM1_GRID) {
        const int blk = blockIdx.x - GEMM1_GRID;
        int* hist = (int*)Wlds;
        if (tid < NBK) hist[tid] = 0;
        __syncthreads();
        const int e0 = blk * EPB;
        if (tid < EPB / 4) {
            int4 d4 = *(const int4*)(ei + NE + e0 + 4 * tid);
            atomicAdd(&hist[d4.x >> 8], 1);
            atomicAdd(&hist[d4.y >> 8], 1);
            atomicAdd(&hist[d4.z >> 8], 1);
            atomicAdd(&hist[d4.w >> 8], 1);
        }
        // side job: pack W2 (split precision) for the gemm2 dispatch
        if (blk < 64 && tid < 256) {
            int idx = blk * 256 + tid;          // 0..16383
            int k = idx >> 7, n = idx & 127;
            float f = W2[idx];
            ushort hb = f2bf_bits(f);
            union { ushort u; __hip_bfloat16 h; } c; c.u = hb;
            float lo = f - __bfloat162float(c.h);
            wt[n * WKP + k] = hb;
            wt[WPLANE + n * WKP + k] = f2bf_bits(lo);
        }
        __syncthreads();
        if (tid < NBK) blockHist[tid * HBLK + blk] = hist[tid];
        return;
    }

    // ---- layer-1 GEMM (f32 input, split precision), 16 waves ----
    for (int i = tid; i < FH * 128; i += 1024) {
        int k = i >> 7, n = i & 127;
        float f = W1[i];                        // W1[k*128+n]
        ushort hb = f2bf_bits(f);
        union { ushort u; __hip_bfloat16 h; } c; c.u = hb;
        float lo = f - __bfloat162float(c.h);
        Wlds[n * WKP + k] = hb;
        Wlds[WPLANE + n * WKP + k] = f2bf_bits(lo);
    }
    __syncthreads();

    const int wave = tid >> 6;         // 0..15
    const int lane = tid & 63;
    const int quad = lane >> 4;
    const int l16 = lane & 15;
    const int row0 = blockIdx.x * 256 + wave * 16;

    f32x4 acc[8];
#pragma unroll
    for (int t = 0; t < 8; ++t) acc[t] = (f32x4){0.f, 0.f, 0.f, 0.f};

    int arow = row0 + l16; if (arow >= NN) arow = NN - 1;
    const float* ap = A + (size_t)arow * FH + quad * 8;

#pragma unroll
    for (int kc = 0; kc < 4; ++kc) {
        float4 x0 = *(const float4*)(ap + kc * 32);
        float4 x1 = *(const float4*)(ap + kc * 32 + 4);
        float av[8] = {x0.x, x0.y, x0.z, x0.w, x1.x, x1.y, x1.z, x1.w};
        short8 ah, al;
#pragma unroll
        for (int j = 0; j < 8; ++j) {
            ushort hb = f2bf_bits(av[j]);
            union { ushort u; __hip_bfloat16 h; } c; c.u = hb;
            float lo = av[j] - __bfloat162float(c.h);
            ah[j] = (short)hb;
            al[j] = (short)f2bf_bits(lo);
        }
        const int kof = kc * 32 + quad * 8;
#pragma unroll
        for (int t = 0; t < 8; ++t) {
            const ushort* wp = &Wlds[(t * 16 + l16) * WKP + kof];
            short8 wh = *(const short8*)wp;
            short8 wl = *(const short8*)(wp + WPLANE);
            acc[t] = __builtin_amdgcn_mfma_f32_16x16x32_bf16(ah, wh, acc[t], 0, 0, 0);
            acc[t] = __builtin_amdgcn_mfma_f32_16x16x32_bf16(al, wh, acc[t], 0, 0, 0);
            acc[t] = __builtin_amdgcn_mfma_f32_16x16x32_bf16(ah, wl, acc[t], 0, 0, 0);
        }
    }
    GEMM_EPILOGUE()
}

// ---------------------------------------------------------------------------
// Merged scan (unchanged).
// ---------------------------------------------------------------------------
__global__ __launch_bounds__(256) void scanAB_kernel(const int* __restrict__ bh,
                                                     int* __restrict__ bstart,
                                                     int* __restrict__ ebase,
                                                     int* __restrict__ offs) {
    __shared__ int sd[256];
    __shared__ int bprefix;
    const int b = blockIdx.x, t = threadIdx.x;
    int v = 0;
    if (t < NBK) {
        const int* p = bh + t * HBLK;
        for (int i = 0; i < HBLK; ++i) v += p[i];
    }
    sd[t] = v; __syncthreads();
#pragma unroll
    for (int o = 1; o < 256; o <<= 1) {
        int u = (t >= o) ? sd[t - o] : 0;
        __syncthreads();
        sd[t] += u;
        __syncthreads();
    }
    if (t == b) bprefix = sd[t] - v;   // exclusive prefix for this bucket
    if (b == 0) {
        if (t < NBK) ebase[t] = sd[t] - v;
        if (t == NBK - 1) ebase[NBK] = sd[t];   // == NE
        if (t == 0) offs[NN] = ET;
    }
    __syncthreads();
    const int base = bprefix;
    __syncthreads();
    int c = (t < HBLK) ? bh[b * HBLK + t] : 0;
    sd[t] = c; __syncthreads();
#pragma unroll
    for (int o = 1; o < 256; o <<= 1) {
        int u = (t >= o) ? sd[t - o] : 0;
        __syncthreads();
        sd[t] += u;
        __syncthreads();
    }
    if (t < HBLK) bstart[b * HBLK + t] = base + sd[t] - c;
}

// ---------------------------------------------------------------------------
// Bucket scatter (unchanged).
// ---------------------------------------------------------------------------
__global__ __launch_bounds__(1024) void bucket_scatter_kernel(
    const int* __restrict__ ei, const int* __restrict__ bstart,
    int2* __restrict__ ebuf) {
    __shared__ int cur[NBK];
    const int tid = threadIdx.x;
    const int blk = blockIdx.x;
    for (int i = tid; i < NBK; i += 1024) cur[i] = bstart[i * HBLK + blk];
    __syncthreads();
    const int e0 = blk * EPB;
    if (tid < EPB / 4) {
        int4 d4 = *(const int4*)(ei + NE + e0 + 4 * tid);
        int4 s4 = *(const int4*)(ei + e0 + 4 * tid);
        int ds[4] = {d4.x, d4.y, d4.z, d4.w};
        int ss[4] = {s4.x, s4.y, s4.z, s4.w};
#pragma unroll
        for (int j = 0; j < 4; ++j) {
            int pos = atomicAdd(&cur[ds[j] >> 8], 1);
            ebuf[pos] = make_int2(ss[j], ds[j]);
        }
    }
}

// ---------------------------------------------------------------------------
// Per-bucket CSR finalize (unchanged).
// ---------------------------------------------------------------------------
__global__ __launch_bounds__(256) void bucket_csr_kernel(
    const int2* __restrict__ ebuf, const int* __restrict__ ebase,
    int* __restrict__ offs, int* __restrict__ csrc) {
    __shared__ int hist[256];
    __shared__ int sd[256];
    __shared__ int cur[256];
    const int b = blockIdx.x, t = threadIdx.x;
    const int lo = b << 8;
    int psz = NN - lo; if (psz > 256) psz = 256;
    const int e0 = ebase[b], e1 = ebase[b + 1];

    hist[t] = 0;
    __syncthreads();
    for (int k = e0 + t; k < e1; k += 256) {
        int2 e = ebuf[k];
        atomicAdd(&hist[e.y - lo], 1);
    }
    __syncthreads();
    const int d = hist[t];
    sd[t] = d; __syncthreads();
#pragma unroll
    for (int o = 1; o < 256; o <<= 1) {
        int u = (t >= o) ? sd[t - o] : 0;
        __syncthreads();
        sd[t] += u;
        __syncthreads();
    }
    const int ex = sd[t] - d;
    if (t < psz) {
        const int node = lo + t;
        const int o = e0 + ex + node;
        offs[node] = o;
        cur[t] = o;
        csrc[o + d] = node;             // self loop at end of the node's range
    }
    __syncthreads();
    for (int k = e0 + t; k < e1; k += 256) {
        int2 e = ebuf[k];
        int pos = atomicAdd(&cur[e.y - lo], 1);
        csrc[pos] = e.x;
    }
}

// ---------------------------------------------------------------------------
// Layer-2 GEMM, 1024-thread / 256-row blocks (196 blocks): one W-LDS fill
// per 256 output rows instead of per 64 (782x69.6KB -> 196x69.6KB L2 reads).
// ---------------------------------------------------------------------------
__global__ __launch_bounds__(1024) void gemm_att_bf16_kernel(
    const __hip_bfloat16* __restrict__ A, const ushort* __restrict__ wt,
    const float* __restrict__ att_s, const float* __restrict__ att_d,
    __hip_bfloat16* __restrict__ Hb, float* __restrict__ a_src, float* __restrict__ a_dst)
{
    __shared__ __align__(16) ushort Wlds[2 * WPLANE];
    const int tid = threadIdx.x;
    {
        const uint4* s = (const uint4*)wt;
        uint4* d = (uint4*)Wlds;
        for (int i = tid; i < 2 * WPLANE / 8; i += 1024) d[i] = s[i];
    }
    __syncthreads();

    const int wave = tid >> 6;         // 0..15
    const int lane = tid & 63;
    const int quad = lane >> 4;
    const int l16 = lane & 15;
    const int row0 = blockIdx.x * 256 + wave * 16;

    f32x4 acc[8];
#pragma unroll
    for (int t = 0; t < 8; ++t) acc[t] = (f32x4){0.f, 0.f, 0.f, 0.f};

    int arow = row0 + l16; if (arow >= NN) arow = NN - 1;
    const __hip_bfloat16* ap = A + (size_t)arow * FH + quad * 8;

#pragma unroll
    for (int kc = 0; kc < 4; ++kc) {
        short8 ah = *(const short8*)(ap + kc * 32);
        const int kof = kc * 32 + quad * 8;
#pragma unroll
        for (int t = 0; t < 8; ++t) {
            const ushort* wp = &Wlds[(t * 16 + l16) * WKP + kof];
            short8 wh = *(const short8*)wp;
            short8 wl = *(const short8*)(wp + WPLANE);
            acc[t] = __builtin_amdgcn_mfma_f32_16x16x32_bf16(ah, wh, acc[t], 0, 0, 0);
            acc[t] = __builtin_amdgcn_mfma_f32_16x16x32_bf16(ah, wl, acc[t], 0, 0, 0);
        }
    }
    GEMM_EPILOGUE()
}

// ---------------------------------------------------------------------------
// Per-node aggregation, one wave per node, CONSUMER-ONLY straight-line form
// (round-5 known-good). Gather is fabric-throughput-bound (~4.2 TB/s on
// 205MB/layer random row reads) -- do not re-micro-optimize (rounds 4-6).
// ---------------------------------------------------------------------------
__global__ __launch_bounds__(256) void gat_agg_kernel(
    const __hip_bfloat16* __restrict__ Hb, const float* __restrict__ asrc,
    const float* __restrict__ adst, const int* __restrict__ offs,
    const int* __restrict__ csrc, const float* __restrict__ bias,
    __hip_bfloat16* __restrict__ out)
{
    const int wid = threadIdx.x >> 6;
    const int lane = threadIdx.x & 63;
    const int n = blockIdx.x * 4 + wid;   // NN % 4 == 0, no bounds check

    const int beg = offs[n], end = offs[n + 1];
    const int es = lane >> 4;      // edge sub-slot 0..3
    const int fs = lane & 15;      // feature slot (8 feats each)
    const int hC = fs >> 2;        // head of these features
    const int f8 = fs * 8;
    const float adC = adst[n * NHEAD + hC];

    float dsum = 0.f;
    float acc[8];
#pragma unroll
    for (int i = 0; i < 8; ++i) acc[i] = 0.f;

    const int last = end - 1;
    const int n8 = (end - beg + 7) >> 3;
    for (int p = 0; p < n8; ++p) {
        const int eA = beg + 8 * p + es;
        const int eB = eA + 4;
        const bool vA = eA < end, vB = eB < end;
        const int sA = csrc[vA ? eA : last];
        const int sB = csrc[vB ? eB : last];
        float aA = asrc[sA * NHEAD + hC] + adC;
        float aB = asrc[sB * NHEAD + hC] + adC;
        aA = aA > 0.f ? aA : 0.2f * aA;
        aB = aB > 0.f ? aB : 0.2f * aB;
        const float wA = vA ? __expf(aA) : 0.f;
        const float wB = vB ? __expf(aB) : 0.f;
        dsum += wA + wB;
        union { uint4 u; __hip_bfloat162 b[4]; } cvA, cvB;
        cvA.u = *(const uint4*)&Hb[(size_t)sA * FH + f8];
        cvB.u = *(const uint4*)&Hb[(size_t)sB * FH + f8];
#pragma unroll
        for (int i = 0; i < 4; ++i) {
            float2 hA = __bfloat1622float2(cvA.b[i]);
            float2 hB2 = __bfloat1622float2(cvB.b[i]);
            acc[2 * i]     = fmaf(wA, hA.x, acc[2 * i]);
            acc[2 * i + 1] = fmaf(wA, hA.y, acc[2 * i + 1]);
            acc[2 * i]     = fmaf(wB, hB2.x, acc[2 * i]);
            acc[2 * i + 1] = fmaf(wB, hB2.y, acc[2 * i + 1]);
        }
    }
    dsum += __shfl_xor(dsum, 1);
    dsum += __shfl_xor(dsum, 2);
    dsum += __shfl_xor(dsum, 16);
    dsum += __shfl_xor(dsum, 32);
#pragma unroll
    for (int i = 0; i < 8; ++i) {
        acc[i] += __shfl_xor(acc[i], 16);
        acc[i] += __shfl_xor(acc[i], 32);
    }
    const float inv = 4.0f / dsum;   // each (edge,head) counted by 4 lanes
    if (es == 0) {
        union { ushort u8[8]; uint4 u; } pk;
#pragma unroll
        for (int i = 0; i < 8; ++i) {
            float v = fmaxf(fmaf(acc[i], inv, bias[f8 + i]), 0.f);
            pk.u8[i] = f2bf_bits(v);
        }
        *(uint4*)&out[(size_t)n * FH + f8] = pk.u;
    }
}

// ---------------------------------------------------------------------------
// Mean pool + final linear fused (unchanged).
// ---------------------------------------------------------------------------
__global__ __launch_bounds__(256) void pool_final_kernel(
    const __hip_bfloat16* __restrict__ X, const int* __restrict__ batch,
    const float* __restrict__ wl, const float* __restrict__ bl,
    float* __restrict__ out)
{
    const int g = blockIdx.x;
    const int t = threadIdx.x;
    int a = 0, b = NN;
    while (a < b) { int m = (a + b) >> 1; if (batch[m] < g) a = m + 1; else b = m; }
    const int gs = a;
    b = NN;
    while (a < b) { int m = (a + b) >> 1; if (batch[m] <= g) a = m + 1; else b = m; }
    const int ge = a;

    const int rg = t >> 4;
    const int l16 = t & 15;
    float acc[8];
#pragma unroll
    for (int i = 0; i < 8; ++i) acc[i] = 0.f;
    for (int r = gs + rg; r < ge; r += 16) {
        union { uint4 u; __hip_bfloat162 bb[4]; } cv;
        cv.u = *(const uint4*)&X[(size_t)r * FH + l16 * 8];
#pragma unroll
        for (int i = 0; i < 4; ++i) {
            float2 f = __bfloat1622float2(cv.bb[i]);
            acc[2 * i]     += f.x;
            acc[2 * i + 1] += f.y;
        }
    }
    __shared__ float red[16][128];
    __shared__ float pl[128];
#pragma unroll
    for (int i = 0; i < 8; ++i) red[rg][l16 * 8 + i] = acc[i];
    __syncthreads();
    if (t < 128) {
        float s = 0.f;
#pragma unroll
        for (int j = 0; j < 16; ++j) s += red[j][t];
        pl[t] = s;
    }
    __syncthreads();
    if (t < OC) {
        float invc = 1.0f / fmaxf((float)(ge - gs), 1.0f);
        float a2 = 0.f;
        for (int k = 0; k < FH; ++k)
            a2 = fmaf(pl[k], wl[k * OC + t], a2);
        out[g * OC + t] = a2 * invc + bl[t];
    }
}

// ---------------------------------------------------------------------------
extern "C" void kernel_launch(void* const* d_in, const int* in_sizes, int n_in,
                              void* d_out, int out_size, void* d_ws, size_t ws_size,
                              hipStream_t stream) {
    const float* x       = (const float*)d_in[0];
    const int*   ei      = (const int*)d_in[1];   // [2, NE]
    const int*   batch   = (const int*)d_in[2];
    const float* W1      = (const float*)d_in[3];
    const float* as1     = (const float*)d_in[4];
    const float* ad1     = (const float*)d_in[5];
    const float* b1      = (const float*)d_in[6];
    const float* W2      = (const float*)d_in[7];
    const float* as2     = (const float*)d_in[8];
    const float* ad2     = (const float*)d_in[9];
    const float* b2      = (const float*)d_in[10];
    const float* wlin    = (const float*)d_in[11];
    const float* blin    = (const float*)d_in[12];
    float* out = (float*)d_out;

    // workspace layout (everything fully rewritten each call -> no memset)
    __hip_bfloat16* hbuf = (__hip_bfloat16*)d_ws;        // NN*FH bf16 (gemm out)
    __hip_bfloat16* abuf = hbuf + (size_t)NN * FH;       // NN*FH bf16 (agg out)
    float* asrc  = (float*)(abuf + (size_t)NN * FH);     // NN*4
    float* adst  = asrc + (size_t)NN * NHEAD;            // NN*4
    int* offs    = (int*)(adst + (size_t)NN * NHEAD);    // NN+1
    int* csrc    = offs + NN + 1;                        // ET
    int2* ebuf   = (int2*)(((uintptr_t)(csrc + ET) + 7) & ~(uintptr_t)7); // NE int2
    int* bh      = (int*)(ebuf + NE);         // NBK*HBLK
    int* bstart  = bh + NBK * HBLK;           // NBK*HBLK
    int* ebase   = bstart + NBK * HBLK;       // NBK+1
    ushort* wt   = (ushort*)(((uintptr_t)(ebase + NBK + 1) + 15) & ~(uintptr_t)15); // 2*WPLANE

    // 1. Fused: layer-1 GEMM (in-kernel W1 pack) + bucket hist + W2 pack
    fused_gemm_hist_kernel<<<GEMM1_GRID + HBLK, 1024, 0, stream>>>(
        ei, bh, x, W1, W2, wt, as1, ad1, hbuf, asrc, adst);

    // 2-4. CSR build
    scanAB_kernel<<<NBK, 256, 0, stream>>>(bh, bstart, ebase, offs);
    bucket_scatter_kernel<<<HBLK, 1024, 0, stream>>>(ei, bstart, ebuf);
    bucket_csr_kernel<<<NBK, 256, 0, stream>>>(ebuf, ebase, offs, csrc);

    const int agg_grid = NN / 4;

    // 5. Layer 1 aggregation
    gat_agg_kernel<<<agg_grid, 256, 0, stream>>>(hbuf, asrc, adst, offs, csrc, b1, abuf);
    // 6. Layer 2 GEMM (1024-thr / 256-row blocks)
    gemm_att_bf16_kernel<<<GEMM2_GRID, 1024, 0, stream>>>(abuf, wt, as2, ad2, hbuf, asrc, adst);
    // 7. Layer 2 aggregation
    gat_agg_kernel<<<agg_grid, 256, 0, stream>>>(hbuf, asrc, adst, offs, csrc, b2, abuf);

    // 8. Pool + final linear (fused)
    pool_final_kernel<<<NG, 256, 0, stream>>>(abuf, batch, wlin, blin, out);
}

// Round 9
// 246.286 us; speedup vs baseline: 1.1025x; 1.0090x over previous
//
#include <hip/hip_runtime.h>
#include <hip/hip_bf16.h>
#include <math.h>

// Problem constants
constexpr int NN = 50000;   // nodes
constexpr int NE = 800000;  // edges (without self loops)
constexpr int ET = NE + NN; // edges + self loops
constexpr int FH = 128;     // HEADS*HID = feature width (also IN_CH)
constexpr int NHEAD = 4;
constexpr int NG = 64;      // graphs
constexpr int OC = 10;      // out channels

// Multisplit CSR build: buckets of 256 nodes (bucket = dst >> 8).
// Zero global atomics anywhere in the data path (global atomics write
// through to the memory side, ~32B each -- round-1 counters).
// NOTE (round 8): intra-kernel sub-grid barriers hung the container --
// keep the CSR chain as separate stream-ordered dispatches.
constexpr int NBK = (NN + 255) >> 8;   // 196 buckets
constexpr int EPB = 4000;              // edges per hist/scatter block
constexpr int HBLK = NE / EPB;         // 200 blocks

// W^T pack: [128 n][136 k] ushort, padded to 136 for LDS bank stagger
constexpr int WKP = 136;
constexpr int WPLANE = 128 * WKP;   // ushorts per plane (hi or lo)

constexpr int GEMM1_GRID = (NN + 255) / 256;  // 196 blocks x 1024 thr (16 waves)
constexpr int GEMM2_GRID = (NN + 255) / 256;  // 196 blocks x 1024 thr (16 waves)

typedef __attribute__((ext_vector_type(8))) short short8;
typedef __attribute__((ext_vector_type(4))) float f32x4;

__device__ inline ushort f2bf_bits(float f) {
    union { __hip_bfloat16 h; ushort u; } c;
    c.h = __float2bfloat16(f);
    return c.u;
}

// ---------------------------------------------------------------------------
// MFMA GEMM + attention epilogue (per-wave; wave/row0 set by caller).
// C/D layout: col=lane&15, row=quad*4+reg.
// ---------------------------------------------------------------------------
#define GEMM_EPILOGUE()                                                          \
    float as_[8], ad_[8];                                                        \
    _Pragma("unroll")                                                            \
    for (int t = 0; t < 8; ++t) {                                                \
        as_[t] = att_s[t * 16 + l16];                                            \
        ad_[t] = att_d[t * 16 + l16];                                            \
    }                                                                            \
    float hs[4][4], hd[4][4];                                                    \
    _Pragma("unroll")                                                            \
    for (int r = 0; r < 4; ++r) {                                                \
        int grow = row0 + quad * 4 + r;                                          \
        bool okr = (grow < NN);                                                  \
        _Pragma("unroll")                                                        \
        for (int h = 0; h < 4; ++h) {                                            \
            hs[r][h] = acc[2*h][r] * as_[2*h] + acc[2*h+1][r] * as_[2*h+1];      \
            hd[r][h] = acc[2*h][r] * ad_[2*h] + acc[2*h+1][r] * ad_[2*h+1];      \
        }                                                                        \
        if (okr) {                                                               \
            _Pragma("unroll")                                                    \
            for (int t = 0; t < 8; ++t)                                          \
                Hb[(size_t)grow * FH + t * 16 + l16] = __float2bfloat16(acc[t][r]); \
        }                                                                        \
    }                                                                            \
    _Pragma("unroll")                                                            \
    for (int o = 1; o < 16; o <<= 1) {                                           \
        _Pragma("unroll")                                                        \
        for (int r = 0; r < 4; ++r)                                              \
            _Pragma("unroll")                                                    \
            for (int h = 0; h < 4; ++h) {                                        \
                hs[r][h] += __shfl_xor(hs[r][h], o);                             \
                hd[r][h] += __shfl_xor(hd[r][h], o);                             \
            }                                                                    \
    }                                                                            \
    if (l16 == 0) {                                                              \
        _Pragma("unroll")                                                        \
        for (int r = 0; r < 4; ++r) {                                            \
            int grow = row0 + quad * 4 + r;                                      \
            if (grow < NN) {                                                     \
                *(float4*)&a_src[grow * NHEAD] = make_float4(hs[r][0], hs[r][1], hs[r][2], hs[r][3]); \
                *(float4*)&a_dst[grow * NHEAD] = make_float4(hd[r][0], hd[r][1], hd[r][2], hd[r][3]); \
            }                                                                    \
        }                                                                        \
    }

// ---------------------------------------------------------------------------
// Fused dispatch (1024 threads):
//  blocks [0, GEMM1_GRID): layer-1 GEMM; converts W1 f32 -> split-bf16 LDS
//    in-kernel.
//  blocks [GEMM1_GRID, +HBLK): per-block bucket histogram (LDS atomics only,
//    plain stores) + side job: first 64 of them pack W2 into wt (read only
//    by the later gemm2 dispatch).
// ---------------------------------------------------------------------------
__global__ __launch_bounds__(1024) void fused_gemm_hist_kernel(
    const int* __restrict__ ei, int* __restrict__ blockHist,
    const float* __restrict__ A, const float* __restrict__ W1,
    const float* __restrict__ W2, ushort* __restrict__ wt,
    const float* __restrict__ att_s, const float* __restrict__ att_d,
    __hip_bfloat16* __restrict__ Hb, float* __restrict__ a_src, float* __restrict__ a_dst)
{
    __shared__ __align__(16) ushort Wlds[2 * WPLANE];
    const int tid = threadIdx.x;

    if (blockIdx.x >= GEMM1_GRID) {
        const int blk = blockIdx.x - GEMM1_GRID;
        int* hist = (int*)Wlds;
        if (tid < NBK) hist[tid] = 0;
        __syncthreads();
        const int e0 = blk * EPB;
        if (tid < EPB / 4) {
            int4 d4 = *(const int4*)(ei + NE + e0 + 4 * tid);
            atomicAdd(&hist[d4.x >> 8], 1);
            atomicAdd(&hist[d4.y >> 8], 1);
            atomicAdd(&hist[d4.z >> 8], 1);
            atomicAdd(&hist[d4.w >> 8], 1);
        }
        // side job: pack W2 (split precision) for the gemm2 dispatch
        if (blk < 64 && tid < 256) {
            int idx = blk * 256 + tid;          // 0..16383
            int k = idx >> 7, n = idx & 127;
            float f = W2[idx];
            ushort hb = f2bf_bits(f);
            union { ushort u; __hip_bfloat16 h; } c; c.u = hb;
            float lo = f - __bfloat162float(c.h);
            wt[n * WKP + k] = hb;
            wt[WPLANE + n * WKP + k] = f2bf_bits(lo);
        }
        __syncthreads();
        if (tid < NBK) blockHist[tid * HBLK + blk] = hist[tid];
        return;
    }

    // ---- layer-1 GEMM (f32 input, split precision), 16 waves ----
    for (int i = tid; i < FH * 128; i += 1024) {
        int k = i >> 7, n = i & 127;
        float f = W1[i];                        // W1[k*128+n]
        ushort hb = f2bf_bits(f);
        union { ushort u; __hip_bfloat16 h; } c; c.u = hb;
        float lo = f - __bfloat162float(c.h);
        Wlds[n * WKP + k] = hb;
        Wlds[WPLANE + n * WKP + k] = f2bf_bits(lo);
    }
    __syncthreads();

    const int wave = tid >> 6;         // 0..15
    const int lane = tid & 63;
    const int quad = lane >> 4;
    const int l16 = lane & 15;
    const int row0 = blockIdx.x * 256 + wave * 16;

    f32x4 acc[8];
#pragma unroll
    for (int t = 0; t < 8; ++t) acc[t] = (f32x4){0.f, 0.f, 0.f, 0.f};

    int arow = row0 + l16; if (arow >= NN) arow = NN - 1;
    const float* ap = A + (size_t)arow * FH + quad * 8;

#pragma unroll
    for (int kc = 0; kc < 4; ++kc) {
        float4 x0 = *(const float4*)(ap + kc * 32);
        float4 x1 = *(const float4*)(ap + kc * 32 + 4);
        float av[8] = {x0.x, x0.y, x0.z, x0.w, x1.x, x1.y, x1.z, x1.w};
        short8 ah, al;
#pragma unroll
        for (int j = 0; j < 8; ++j) {
            ushort hb = f2bf_bits(av[j]);
            union { ushort u; __hip_bfloat16 h; } c; c.u = hb;
            float lo = av[j] - __bfloat162float(c.h);
            ah[j] = (short)hb;
            al[j] = (short)f2bf_bits(lo);
        }
        const int kof = kc * 32 + quad * 8;
#pragma unroll
        for (int t = 0; t < 8; ++t) {
            const ushort* wp = &Wlds[(t * 16 + l16) * WKP + kof];
            short8 wh = *(const short8*)wp;
            short8 wl = *(const short8*)(wp + WPLANE);
            acc[t] = __builtin_amdgcn_mfma_f32_16x16x32_bf16(ah, wh, acc[t], 0, 0, 0);
            acc[t] = __builtin_amdgcn_mfma_f32_16x16x32_bf16(al, wh, acc[t], 0, 0, 0);
            acc[t] = __builtin_amdgcn_mfma_f32_16x16x32_bf16(ah, wl, acc[t], 0, 0, 0);
        }
    }
    GEMM_EPILOGUE()
}

// ---------------------------------------------------------------------------
// Bucket scatter with INLINE scan (replaces the separate scanAB dispatch):
// thread i (i < NBK) sums bucket i's HBLK block-counts, recording the prefix
// up to this block's own index; an LDS scan over the 196 bucket totals gives
// the global bucket base; cur[i] = base_i + prefix_i. Redundant per block
// (~150KB L2-hit loads) but fully parallel -> wall cost ~ one block's scan.
// Block 0 publishes ebase[] and offs[NN] for bucket_csr (next dispatch).
// ---------------------------------------------------------------------------
__global__ __launch_bounds__(1024) void bucket_scatter_kernel(
    const int* __restrict__ ei, const int* __restrict__ bh,
    int* __restrict__ ebase, int* __restrict__ offs,
    int2* __restrict__ ebuf) {
    __shared__ int sd[256];
    __shared__ int cur[NBK];
    const int tid = threadIdx.x;
    const int blk = blockIdx.x;

    int total = 0, pre = 0;
    if (tid < NBK) {
        const int* p = bh + tid * HBLK;
        for (int j = 0; j < HBLK; ++j) {
            int v = p[j];
            pre += (j < blk) ? v : 0;
            total += v;
        }
    }
    if (tid < 256) sd[tid] = (tid < NBK) ? total : 0;
    __syncthreads();
    for (int o = 1; o < 256; o <<= 1) {
        int u = (tid < 256 && tid >= o) ? sd[tid - o] : 0;
        __syncthreads();
        if (tid < 256) sd[tid] += u;
        __syncthreads();
    }
    if (tid < NBK) {
        const int base = sd[tid] - total;   // exclusive bucket base
        cur[tid] = base + pre;
        if (blk == 0) {
            ebase[tid] = base;
            if (tid == NBK - 1) { ebase[NBK] = sd[tid]; offs[NN] = ET; }
        }
    }
    __syncthreads();

    const int e0 = blk * EPB;
    if (tid < EPB / 4) {
        int4 d4 = *(const int4*)(ei + NE + e0 + 4 * tid);
        int4 s4 = *(const int4*)(ei + e0 + 4 * tid);
        int ds[4] = {d4.x, d4.y, d4.z, d4.w};
        int ss[4] = {s4.x, s4.y, s4.z, s4.w};
#pragma unroll
        for (int j = 0; j < 4; ++j) {
            int pos = atomicAdd(&cur[ds[j] >> 8], 1);
            ebuf[pos] = make_int2(ss[j], ds[j]);
        }
    }
}

// ---------------------------------------------------------------------------
// Per-bucket CSR finalize (unchanged).
// ---------------------------------------------------------------------------
__global__ __launch_bounds__(256) void bucket_csr_kernel(
    const int2* __restrict__ ebuf, const int* __restrict__ ebase,
    int* __restrict__ offs, int* __restrict__ csrc) {
    __shared__ int hist[256];
    __shared__ int sd[256];
    __shared__ int cur[256];
    const int b = blockIdx.x, t = threadIdx.x;
    const int lo = b << 8;
    int psz = NN - lo; if (psz > 256) psz = 256;
    const int e0 = ebase[b], e1 = ebase[b + 1];

    hist[t] = 0;
    __syncthreads();
    for (int k = e0 + t; k < e1; k += 256) {
        int2 e = ebuf[k];
        atomicAdd(&hist[e.y - lo], 1);
    }
    __syncthreads();
    const int d = hist[t];
    sd[t] = d; __syncthreads();
#pragma unroll
    for (int o = 1; o < 256; o <<= 1) {
        int u = (t >= o) ? sd[t - o] : 0;
        __syncthreads();
        sd[t] += u;
        __syncthreads();
    }
    const int ex = sd[t] - d;
    if (t < psz) {
        const int node = lo + t;
        const int o = e0 + ex + node;
        offs[node] = o;
        cur[t] = o;
        csrc[o + d] = node;             // self loop at end of the node's range
    }
    __syncthreads();
    for (int k = e0 + t; k < e1; k += 256) {
        int2 e = ebuf[k];
        int pos = atomicAdd(&cur[e.y - lo], 1);
        csrc[pos] = e.x;
    }
}

// ---------------------------------------------------------------------------
// Layer-2 GEMM, 1024-thread / 256-row blocks (unchanged from round 7).
// ---------------------------------------------------------------------------
__global__ __launch_bounds__(1024) void gemm_att_bf16_kernel(
    const __hip_bfloat16* __restrict__ A, const ushort* __restrict__ wt,
    const float* __restrict__ att_s, const float* __restrict__ att_d,
    __hip_bfloat16* __restrict__ Hb, float* __restrict__ a_src, float* __restrict__ a_dst)
{
    __shared__ __align__(16) ushort Wlds[2 * WPLANE];
    const int tid = threadIdx.x;
    {
        const uint4* s = (const uint4*)wt;
        uint4* d = (uint4*)Wlds;
        for (int i = tid; i < 2 * WPLANE / 8; i += 1024) d[i] = s[i];
    }
    __syncthreads();

    const int wave = tid >> 6;         // 0..15
    const int lane = tid & 63;
    const int quad = lane >> 4;
    const int l16 = lane & 15;
    const int row0 = blockIdx.x * 256 + wave * 16;

    f32x4 acc[8];
#pragma unroll
    for (int t = 0; t < 8; ++t) acc[t] = (f32x4){0.f, 0.f, 0.f, 0.f};

    int arow = row0 + l16; if (arow >= NN) arow = NN - 1;
    const __hip_bfloat16* ap = A + (size_t)arow * FH + quad * 8;

#pragma unroll
    for (int kc = 0; kc < 4; ++kc) {
        short8 ah = *(const short8*)(ap + kc * 32);
        const int kof = kc * 32 + quad * 8;
#pragma unroll
        for (int t = 0; t < 8; ++t) {
            const ushort* wp = &Wlds[(t * 16 + l16) * WKP + kof];
            short8 wh = *(const short8*)wp;
            short8 wl = *(const short8*)(wp + WPLANE);
            acc[t] = __builtin_amdgcn_mfma_f32_16x16x32_bf16(ah, wh, acc[t], 0, 0, 0);
            acc[t] = __builtin_amdgcn_mfma_f32_16x16x32_bf16(ah, wl, acc[t], 0, 0, 0);
        }
    }
    GEMM_EPILOGUE()
}

// ---------------------------------------------------------------------------
// Per-node aggregation, one wave per node, CONSUMER-ONLY straight-line form
// (round-5 known-good). Gather is fabric-throughput-bound -- do not
// re-micro-optimize (rounds 4-6 all flat).
// ---------------------------------------------------------------------------
__global__ __launch_bounds__(256) void gat_agg_kernel(
    const __hip_bfloat16* __restrict__ Hb, const float* __restrict__ asrc,
    const float* __restrict__ adst, const int* __restrict__ offs,
    const int* __restrict__ csrc, const float* __restrict__ bias,
    __hip_bfloat16* __restrict__ out)
{
    const int wid = threadIdx.x >> 6;
    const int lane = threadIdx.x & 63;
    const int n = blockIdx.x * 4 + wid;   // NN % 4 == 0, no bounds check

    const int beg = offs[n], end = offs[n + 1];
    const int es = lane >> 4;      // edge sub-slot 0..3
    const int fs = lane & 15;      // feature slot (8 feats each)
    const int hC = fs >> 2;        // head of these features
    const int f8 = fs * 8;
    const float adC = adst[n * NHEAD + hC];

    float dsum = 0.f;
    float acc[8];
#pragma unroll
    for (int i = 0; i < 8; ++i) acc[i] = 0.f;

    const int last = end - 1;
    const int n8 = (end - beg + 7) >> 3;
    for (int p = 0; p < n8; ++p) {
        const int eA = beg + 8 * p + es;
        const int eB = eA + 4;
        const bool vA = eA < end, vB = eB < end;
        const int sA = csrc[vA ? eA : last];
        const int sB = csrc[vB ? eB : last];
        float aA = asrc[sA * NHEAD + hC] + adC;
        float aB = asrc[sB * NHEAD + hC] + adC;
        aA = aA > 0.f ? aA : 0.2f * aA;
        aB = aB > 0.f ? aB : 0.2f * aB;
        const float wA = vA ? __expf(aA) : 0.f;
        const float wB = vB ? __expf(aB) : 0.f;
        dsum += wA + wB;
        union { uint4 u; __hip_bfloat162 b[4]; } cvA, cvB;
        cvA.u = *(const uint4*)&Hb[(size_t)sA * FH + f8];
        cvB.u = *(const uint4*)&Hb[(size_t)sB * FH + f8];
#pragma unroll
        for (int i = 0; i < 4; ++i) {
            float2 hA = __bfloat1622float2(cvA.b[i]);
            float2 hB2 = __bfloat1622float2(cvB.b[i]);
            acc[2 * i]     = fmaf(wA, hA.x, acc[2 * i]);
            acc[2 * i + 1] = fmaf(wA, hA.y, acc[2 * i + 1]);
            acc[2 * i]     = fmaf(wB, hB2.x, acc[2 * i]);
            acc[2 * i + 1] = fmaf(wB, hB2.y, acc[2 * i + 1]);
        }
    }
    dsum += __shfl_xor(dsum, 1);
    dsum += __shfl_xor(dsum, 2);
    dsum += __shfl_xor(dsum, 16);
    dsum += __shfl_xor(dsum, 32);
#pragma unroll
    for (int i = 0; i < 8; ++i) {
        acc[i] += __shfl_xor(acc[i], 16);
        acc[i] += __shfl_xor(acc[i], 32);
    }
    const float inv = 4.0f / dsum;   // each (edge,head) counted by 4 lanes
    if (es == 0) {
        union { ushort u8[8]; uint4 u; } pk;
#pragma unroll
        for (int i = 0; i < 8; ++i) {
            float v = fmaxf(fmaf(acc[i], inv, bias[f8 + i]), 0.f);
            pk.u8[i] = f2bf_bits(v);
        }
        *(uint4*)&out[(size_t)n * FH + f8] = pk.u;
    }
}

// ---------------------------------------------------------------------------
// Mean pool + final linear fused (unchanged).
// ---------------------------------------------------------------------------
__global__ __launch_bounds__(256) void pool_final_kernel(
    const __hip_bfloat16* __restrict__ X, const int* __restrict__ batch,
    const float* __restrict__ wl, const float* __restrict__ bl,
    float* __restrict__ out)
{
    const int g = blockIdx.x;
    const int t = threadIdx.x;
    int a = 0, b = NN;
    while (a < b) { int m = (a + b) >> 1; if (batch[m] < g) a = m + 1; else b = m; }
    const int gs = a;
    b = NN;
    while (a < b) { int m = (a + b) >> 1; if (batch[m] <= g) a = m + 1; else b = m; }
    const int ge = a;

    const int rg = t >> 4;
    const int l16 = t & 15;
    float acc[8];
#pragma unroll
    for (int i = 0; i < 8; ++i) acc[i] = 0.f;
    for (int r = gs + rg; r < ge; r += 16) {
        union { uint4 u; __hip_bfloat162 bb[4]; } cv;
        cv.u = *(const uint4*)&X[(size_t)r * FH + l16 * 8];
#pragma unroll
        for (int i = 0; i < 4; ++i) {
            float2 f = __bfloat1622float2(cv.bb[i]);
            acc[2 * i]     += f.x;
            acc[2 * i + 1] += f.y;
        }
    }
    __shared__ float red[16][128];
    __shared__ float pl[128];
#pragma unroll
    for (int i = 0; i < 8; ++i) red[rg][l16 * 8 + i] = acc[i];
    __syncthreads();
    if (t < 128) {
        float s = 0.f;
#pragma unroll
        for (int j = 0; j < 16; ++j) s += red[j][t];
        pl[t] = s;
    }
    __syncthreads();
    if (t < OC) {
        float invc = 1.0f / fmaxf((float)(ge - gs), 1.0f);
        float a2 = 0.f;
        for (int k = 0; k < FH; ++k)
            a2 = fmaf(pl[k], wl[k * OC + t], a2);
        out[g * OC + t] = a2 * invc + bl[t];
    }
}

// ---------------------------------------------------------------------------
extern "C" void kernel_launch(void* const* d_in, const int* in_sizes, int n_in,
                              void* d_out, int out_size, void* d_ws, size_t ws_size,
                              hipStream_t stream) {
    const float* x       = (const float*)d_in[0];
    const int*   ei      = (const int*)d_in[1];   // [2, NE]
    const int*   batch   = (const int*)d_in[2];
    const float* W1      = (const float*)d_in[3];
    const float* as1     = (const float*)d_in[4];
    const float* ad1     = (const float*)d_in[5];
    const float* b1      = (const float*)d_in[6];
    const float* W2      = (const float*)d_in[7];
    const float* as2     = (const float*)d_in[8];
    const float* ad2     = (const float*)d_in[9];
    const float* b2      = (const float*)d_in[10];
    const float* wlin    = (const float*)d_in[11];
    const float* blin    = (const float*)d_in[12];
    float* out = (float*)d_out;

    // workspace layout (everything fully rewritten each call -> no memset)
    __hip_bfloat16* hbuf = (__hip_bfloat16*)d_ws;        // NN*FH bf16 (gemm out)
    __hip_bfloat16* abuf = hbuf + (size_t)NN * FH;       // NN*FH bf16 (agg out)
    float* asrc  = (float*)(abuf + (size_t)NN * FH);     // NN*4
    float* adst  = asrc + (size_t)NN * NHEAD;            // NN*4
    int* offs    = (int*)(adst + (size_t)NN * NHEAD);    // NN+1
    int* csrc    = offs + NN + 1;                        // ET
    int2* ebuf   = (int2*)(((uintptr_t)(csrc + ET) + 7) & ~(uintptr_t)7); // NE int2
    int* bh      = (int*)(ebuf + NE);         // NBK*HBLK
    int* ebase   = bh + NBK * HBLK;           // NBK+1
    ushort* wt   = (ushort*)(((uintptr_t)(ebase + NBK + 1) + 15) & ~(uintptr_t)15); // 2*WPLANE

    // 1. Fused: layer-1 GEMM (in-kernel W1 pack) + bucket hist + W2 pack
    fused_gemm_hist_kernel<<<GEMM1_GRID + HBLK, 1024, 0, stream>>>(
        ei, bh, x, W1, W2, wt, as1, ad1, hbuf, asrc, adst);

    // 2-3. CSR build (scan folded into scatter; block 0 publishes ebase/offs[NN])
    bucket_scatter_kernel<<<HBLK, 1024, 0, stream>>>(ei, bh, ebase, offs, ebuf);
    bucket_csr_kernel<<<NBK, 256, 0, stream>>>(ebuf, ebase, offs, csrc);

    const int agg_grid = NN / 4;

    // 4. Layer 1 aggregation
    gat_agg_kernel<<<agg_grid, 256, 0, stream>>>(hbuf, asrc, adst, offs, csrc, b1, abuf);
    // 5. Layer 2 GEMM (1024-thr / 256-row blocks)
    gemm_att_bf16_kernel<<<GEMM2_GRID, 1024, 0, stream>>>(abuf, wt, as2, ad2, hbuf, asrc, adst);
    // 6. Layer 2 aggregation
    gat_agg_kernel<<<agg_grid, 256, 0, stream>>>(hbuf, asrc, adst, offs, csrc, b2, abuf);

    // 7. Pool + final linear (fused)
    pool_final_kernel<<<NG, 256, 0, stream>>>(abuf, batch, wlin, blin, out);
}

// Round 10
// 246.199 us; speedup vs baseline: 1.1029x; 1.0004x over previous
//
#include <hip/hip_runtime.h>
#include <hip/hip_bf16.h>
#include <math.h>

// Problem constants
constexpr int NN = 50000;   // nodes
constexpr int NE = 800000;  // edges (without self loops)
constexpr int ET = NE + NN; // edges + self loops
constexpr int FH = 128;     // HEADS*HID = feature width (also IN_CH)
constexpr int NHEAD = 4;
constexpr int NG = 64;      // graphs
constexpr int OC = 10;      // out channels

// Multisplit CSR build: buckets of 256 nodes (bucket = dst >> 8).
// Zero global atomics anywhere in the data path (global atomics write
// through to the memory side, ~32B each -- round-1 counters).
// NOTE (round 8): intra-kernel sub-grid barriers hung the container --
// keep the CSR chain as separate stream-ordered dispatches.
constexpr int NBK = (NN + 255) >> 8;   // 196 buckets
constexpr int EPB = 4000;              // edges per hist/scatter block
constexpr int HBLK = NE / EPB;         // 200 blocks

// W^T pack: [128 n][136 k] ushort, padded to 136 for LDS bank stagger
constexpr int WKP = 136;
constexpr int WPLANE = 128 * WKP;   // ushorts per plane (hi or lo)

constexpr int GEMM1_GRID = (NN + 255) / 256;  // 196 blocks x 1024 thr (16 waves)
constexpr int GEMM2_GRID = (NN + 255) / 256;  // 196 blocks x 1024 thr (16 waves)

typedef __attribute__((ext_vector_type(8))) short short8;
typedef __attribute__((ext_vector_type(4))) float f32x4;
typedef __attribute__((ext_vector_type(4))) int int4x;
typedef __attribute__((ext_vector_type(4))) unsigned int uint4x;

__device__ inline ushort f2bf_bits(float f) {
    union { __hip_bfloat16 h; ushort u; } c;
    c.h = __float2bfloat16(f);
    return c.u;
}

// nontemporal load helpers: nt reads still PROBE caches (coherence) but do
// not ALLOCATE -- use on single-use streams to keep L2 for Hb/asrc/wt.
__device__ inline int4x nt_load_i4(const int* p) {
    return __builtin_nontemporal_load((const int4x*)p);
}

// ---------------------------------------------------------------------------
// MFMA GEMM + attention epilogue (per-wave; wave/row0 set by caller).
// C/D layout: col=lane&15, row=quad*4+reg.
// ---------------------------------------------------------------------------
#define GEMM_EPILOGUE()                                                          \
    float as_[8], ad_[8];                                                        \
    _Pragma("unroll")                                                            \
    for (int t = 0; t < 8; ++t) {                                                \
        as_[t] = att_s[t * 16 + l16];                                            \
        ad_[t] = att_d[t * 16 + l16];                                            \
    }                                                                            \
    float hs[4][4], hd[4][4];                                                    \
    _Pragma("unroll")                                                            \
    for (int r = 0; r < 4; ++r) {                                                \
        int grow = row0 + quad * 4 + r;                                          \
        bool okr = (grow < NN);                                                  \
        _Pragma("unroll")                                                        \
        for (int h = 0; h < 4; ++h) {                                            \
            hs[r][h] = acc[2*h][r] * as_[2*h] + acc[2*h+1][r] * as_[2*h+1];      \
            hd[r][h] = acc[2*h][r] * ad_[2*h] + acc[2*h+1][r] * ad_[2*h+1];      \
        }                                                                        \
        if (okr) {                                                               \
            _Pragma("unroll")                                                    \
            for (int t = 0; t < 8; ++t)                                          \
                Hb[(size_t)grow * FH + t * 16 + l16] = __float2bfloat16(acc[t][r]); \
        }                                                                        \
    }                                                                            \
    _Pragma("unroll")                                                            \
    for (int o = 1; o < 16; o <<= 1) {                                           \
        _Pragma("unroll")                                                        \
        for (int r = 0; r < 4; ++r)                                              \
            _Pragma("unroll")                                                    \
            for (int h = 0; h < 4; ++h) {                                        \
                hs[r][h] += __shfl_xor(hs[r][h], o);                             \
                hd[r][h] += __shfl_xor(hd[r][h], o);                             \
            }                                                                    \
    }                                                                            \
    if (l16 == 0) {                                                              \
        _Pragma("unroll")                                                        \
        for (int r = 0; r < 4; ++r) {                                            \
            int grow = row0 + quad * 4 + r;                                      \
            if (grow < NN) {                                                     \
                *(float4*)&a_src[grow * NHEAD] = make_float4(hs[r][0], hs[r][1], hs[r][2], hs[r][3]); \
                *(float4*)&a_dst[grow * NHEAD] = make_float4(hd[r][0], hd[r][1], hd[r][2], hd[r][3]); \
            }                                                                    \
        }                                                                        \
    }

// ---------------------------------------------------------------------------
// Fused dispatch (1024 threads):
//  blocks [0, GEMM1_GRID): layer-1 GEMM; converts W1 f32 -> split-bf16 LDS
//    in-kernel.
//  blocks [GEMM1_GRID, +HBLK): per-block bucket histogram (LDS atomics only,
//    plain stores) + side job: first 64 of them pack W2 into wt.
// ---------------------------------------------------------------------------
__global__ __launch_bounds__(1024) void fused_gemm_hist_kernel(
    const int* __restrict__ ei, int* __restrict__ blockHist,
    const float* __restrict__ A, const float* __restrict__ W1,
    const float* __restrict__ W2, ushort* __restrict__ wt,
    const float* __restrict__ att_s, const float* __restrict__ att_d,
    __hip_bfloat16* __restrict__ Hb, float* __restrict__ a_src, float* __restrict__ a_dst)
{
    __shared__ __align__(16) ushort Wlds[2 * WPLANE];
    const int tid = threadIdx.x;

    if (blockIdx.x >= GEMM1_GRID) {
        const int blk = blockIdx.x - GEMM1_GRID;
        int* hist = (int*)Wlds;
        if (tid < NBK) hist[tid] = 0;
        __syncthreads();
        const int e0 = blk * EPB;
        if (tid < EPB / 4) {
            int4 d4 = *(const int4*)(ei + NE + e0 + 4 * tid);
            atomicAdd(&hist[d4.x >> 8], 1);
            atomicAdd(&hist[d4.y >> 8], 1);
            atomicAdd(&hist[d4.z >> 8], 1);
            atomicAdd(&hist[d4.w >> 8], 1);
        }
        // side job: pack W2 (split precision) for the gemm2 dispatch
        if (blk < 64 && tid < 256) {
            int idx = blk * 256 + tid;          // 0..16383
            int k = idx >> 7, n = idx & 127;
            float f = W2[idx];
            ushort hb = f2bf_bits(f);
            union { ushort u; __hip_bfloat16 h; } c; c.u = hb;
            float lo = f - __bfloat162float(c.h);
            wt[n * WKP + k] = hb;
            wt[WPLANE + n * WKP + k] = f2bf_bits(lo);
        }
        __syncthreads();
        if (tid < NBK) blockHist[tid * HBLK + blk] = hist[tid];
        return;
    }

    // ---- layer-1 GEMM (f32 input, split precision), 16 waves ----
    for (int i = tid; i < FH * 128; i += 1024) {
        int k = i >> 7, n = i & 127;
        float f = W1[i];                        // W1[k*128+n]
        ushort hb = f2bf_bits(f);
        union { ushort u; __hip_bfloat16 h; } c; c.u = hb;
        float lo = f - __bfloat162float(c.h);
        Wlds[n * WKP + k] = hb;
        Wlds[WPLANE + n * WKP + k] = f2bf_bits(lo);
    }
    __syncthreads();

    const int wave = tid >> 6;         // 0..15
    const int lane = tid & 63;
    const int quad = lane >> 4;
    const int l16 = lane & 15;
    const int row0 = blockIdx.x * 256 + wave * 16;

    f32x4 acc[8];
#pragma unroll
    for (int t = 0; t < 8; ++t) acc[t] = (f32x4){0.f, 0.f, 0.f, 0.f};

    int arow = row0 + l16; if (arow >= NN) arow = NN - 1;
    const float* ap = A + (size_t)arow * FH + quad * 8;

#pragma unroll
    for (int kc = 0; kc < 4; ++kc) {
        float4 x0 = *(const float4*)(ap + kc * 32);
        float4 x1 = *(const float4*)(ap + kc * 32 + 4);
        float av[8] = {x0.x, x0.y, x0.z, x0.w, x1.x, x1.y, x1.z, x1.w};
        short8 ah, al;
#pragma unroll
        for (int j = 0; j < 8; ++j) {
            ushort hb = f2bf_bits(av[j]);
            union { ushort u; __hip_bfloat16 h; } c; c.u = hb;
            float lo = av[j] - __bfloat162float(c.h);
            ah[j] = (short)hb;
            al[j] = (short)f2bf_bits(lo);
        }
        const int kof = kc * 32 + quad * 8;
#pragma unroll
        for (int t = 0; t < 8; ++t) {
            const ushort* wp = &Wlds[(t * 16 + l16) * WKP + kof];
            short8 wh = *(const short8*)wp;
            short8 wl = *(const short8*)(wp + WPLANE);
            acc[t] = __builtin_amdgcn_mfma_f32_16x16x32_bf16(ah, wh, acc[t], 0, 0, 0);
            acc[t] = __builtin_amdgcn_mfma_f32_16x16x32_bf16(al, wh, acc[t], 0, 0, 0);
            acc[t] = __builtin_amdgcn_mfma_f32_16x16x32_bf16(ah, wl, acc[t], 0, 0, 0);
        }
    }
    GEMM_EPILOGUE()
}

// ---------------------------------------------------------------------------
// Bucket scatter with INLINE scan (round-9 known-good). ei reads are the
// LAST use of the edge list -> nontemporal.
// ---------------------------------------------------------------------------
__global__ __launch_bounds__(1024) void bucket_scatter_kernel(
    const int* __restrict__ ei, const int* __restrict__ bh,
    int* __restrict__ ebase, int* __restrict__ offs,
    int2* __restrict__ ebuf) {
    __shared__ int sd[256];
    __shared__ int cur[NBK];
    const int tid = threadIdx.x;
    const int blk = blockIdx.x;

    int total = 0, pre = 0;
    if (tid < NBK) {
        const int* p = bh + tid * HBLK;
        for (int j = 0; j < HBLK; ++j) {
            int v = p[j];
            pre += (j < blk) ? v : 0;
            total += v;
        }
    }
    if (tid < 256) sd[tid] = (tid < NBK) ? total : 0;
    __syncthreads();
    for (int o = 1; o < 256; o <<= 1) {
        int u = (tid < 256 && tid >= o) ? sd[tid - o] : 0;
        __syncthreads();
        if (tid < 256) sd[tid] += u;
        __syncthreads();
    }
    if (tid < NBK) {
        const int base = sd[tid] - total;   // exclusive bucket base
        cur[tid] = base + pre;
        if (blk == 0) {
            ebase[tid] = base;
            if (tid == NBK - 1) { ebase[NBK] = sd[tid]; offs[NN] = ET; }
        }
    }
    __syncthreads();

    const int e0 = blk * EPB;
    if (tid < EPB / 4) {
        int4x d4 = nt_load_i4(ei + NE + e0 + 4 * tid);
        int4x s4 = nt_load_i4(ei + e0 + 4 * tid);
#pragma unroll
        for (int j = 0; j < 4; ++j) {
            int pos = atomicAdd(&cur[d4[j] >> 8], 1);
            ebuf[pos] = make_int2(s4[j], d4[j]);
        }
    }
}

// ---------------------------------------------------------------------------
// Per-bucket CSR finalize, now 1024 threads (4x fewer loop iterations over
// the ~4K edges/bucket). Scan stays 256-wide with all-thread barriers.
// ebuf is read TWICE within the block (count + place) -> normal loads so the
// ~32KB slice stays L1/L2-hot between passes.
// ---------------------------------------------------------------------------
__global__ __launch_bounds__(1024) void bucket_csr_kernel(
    const int2* __restrict__ ebuf, const int* __restrict__ ebase,
    int* __restrict__ offs, int* __restrict__ csrc) {
    __shared__ int hist[256];
    __shared__ int sd[256];
    __shared__ int cur[256];
    const int b = blockIdx.x, t = threadIdx.x;
    const int lo = b << 8;
    int psz = NN - lo; if (psz > 256) psz = 256;
    const int e0 = ebase[b], e1 = ebase[b + 1];

    if (t < 256) hist[t] = 0;
    __syncthreads();
    for (int k = e0 + t; k < e1; k += 1024) {
        int2 e = ebuf[k];
        atomicAdd(&hist[e.y - lo], 1);
    }
    __syncthreads();
    const int d = (t < 256) ? hist[t] : 0;
    if (t < 256) sd[t] = d;
    __syncthreads();
    for (int o = 1; o < 256; o <<= 1) {
        int u = (t < 256 && t >= o) ? sd[t - o] : 0;
        __syncthreads();
        if (t < 256) sd[t] += u;
        __syncthreads();
    }
    if (t < psz) {
        const int ex = sd[t] - d;
        const int node = lo + t;
        const int o2 = e0 + ex + node;
        offs[node] = o2;
        cur[t] = o2;
        csrc[o2 + d] = node;             // self loop at end of the node's range
    }
    __syncthreads();
    for (int k = e0 + t; k < e1; k += 1024) {
        int2 e = ebuf[k];
        int pos = atomicAdd(&cur[e.y - lo], 1);
        csrc[pos] = e.x;
    }
}

// ---------------------------------------------------------------------------
// Layer-2 GEMM, 1024-thread / 256-row blocks. A rows are single-use ->
// nontemporal loads (keeps L2 for wt and downstream Hb).
// ---------------------------------------------------------------------------
__global__ __launch_bounds__(1024) void gemm_att_bf16_kernel(
    const __hip_bfloat16* __restrict__ A, const ushort* __restrict__ wt,
    const float* __restrict__ att_s, const float* __restrict__ att_d,
    __hip_bfloat16* __restrict__ Hb, float* __restrict__ a_src, float* __restrict__ a_dst)
{
    __shared__ __align__(16) ushort Wlds[2 * WPLANE];
    const int tid = threadIdx.x;
    {
        const uint4* s = (const uint4*)wt;
        uint4* d = (uint4*)Wlds;
        for (int i = tid; i < 2 * WPLANE / 8; i += 1024) d[i] = s[i];
    }
    __syncthreads();

    const int wave = tid >> 6;         // 0..15
    const int lane = tid & 63;
    const int quad = lane >> 4;
    const int l16 = lane & 15;
    const int row0 = blockIdx.x * 256 + wave * 16;

    f32x4 acc[8];
#pragma unroll
    for (int t = 0; t < 8; ++t) acc[t] = (f32x4){0.f, 0.f, 0.f, 0.f};

    int arow = row0 + l16; if (arow >= NN) arow = NN - 1;
    const __hip_bfloat16* ap = A + (size_t)arow * FH + quad * 8;

#pragma unroll
    for (int kc = 0; kc < 4; ++kc) {
        short8 ah = __builtin_nontemporal_load((const short8*)(ap + kc * 32));
        const int kof = kc * 32 + quad * 8;
#pragma unroll
        for (int t = 0; t < 8; ++t) {
            const ushort* wp = &Wlds[(t * 16 + l16) * WKP + kof];
            short8 wh = *(const short8*)wp;
            short8 wl = *(const short8*)(wp + WPLANE);
            acc[t] = __builtin_amdgcn_mfma_f32_16x16x32_bf16(ah, wh, acc[t], 0, 0, 0);
            acc[t] = __builtin_amdgcn_mfma_f32_16x16x32_bf16(ah, wl, acc[t], 0, 0, 0);
        }
    }
    GEMM_EPILOGUE()
}

// ---------------------------------------------------------------------------
// Per-node aggregation, one wave per node, CONSUMER-ONLY straight-line form
// (round-5 known-good). Gather is fabric-throughput-bound -- do not
// re-micro-optimize (rounds 4-6 all flat). csrc is single-use per pass ->
// nontemporal; Hb/asrc keep normal caching.
// ---------------------------------------------------------------------------
__global__ __launch_bounds__(256) void gat_agg_kernel(
    const __hip_bfloat16* __restrict__ Hb, const float* __restrict__ asrc,
    const float* __restrict__ adst, const int* __restrict__ offs,
    const int* __restrict__ csrc, const float* __restrict__ bias,
    __hip_bfloat16* __restrict__ out)
{
    const int wid = threadIdx.x >> 6;
    const int lane = threadIdx.x & 63;
    const int n = blockIdx.x * 4 + wid;   // NN % 4 == 0, no bounds check

    const int beg = offs[n], end = offs[n + 1];
    const int es = lane >> 4;      // edge sub-slot 0..3
    const int fs = lane & 15;      // feature slot (8 feats each)
    const int hC = fs >> 2;        // head of these features
    const int f8 = fs * 8;
    const float adC = adst[n * NHEAD + hC];

    float dsum = 0.f;
    float acc[8];
#pragma unroll
    for (int i = 0; i < 8; ++i) acc[i] = 0.f;

    const int last = end - 1;
    const int n8 = (end - beg + 7) >> 3;
    for (int p = 0; p < n8; ++p) {
        const int eA = beg + 8 * p + es;
        const int eB = eA + 4;
        const bool vA = eA < end, vB = eB < end;
        const int sA = __builtin_nontemporal_load(&csrc[vA ? eA : last]);
        const int sB = __builtin_nontemporal_load(&csrc[vB ? eB : last]);
        float aA = asrc[sA * NHEAD + hC] + adC;
        float aB = asrc[sB * NHEAD + hC] + adC;
        aA = aA > 0.f ? aA : 0.2f * aA;
        aB = aB > 0.f ? aB : 0.2f * aB;
        const float wA = vA ? __expf(aA) : 0.f;
        const float wB = vB ? __expf(aB) : 0.f;
        dsum += wA + wB;
        union { uint4 u; __hip_bfloat162 b[4]; } cvA, cvB;
        cvA.u = *(const uint4*)&Hb[(size_t)sA * FH + f8];
        cvB.u = *(const uint4*)&Hb[(size_t)sB * FH + f8];
#pragma unroll
        for (int i = 0; i < 4; ++i) {
            float2 hA = __bfloat1622float2(cvA.b[i]);
            float2 hB2 = __bfloat1622float2(cvB.b[i]);
            acc[2 * i]     = fmaf(wA, hA.x, acc[2 * i]);
            acc[2 * i + 1] = fmaf(wA, hA.y, acc[2 * i + 1]);
            acc[2 * i]     = fmaf(wB, hB2.x, acc[2 * i]);
            acc[2 * i + 1] = fmaf(wB, hB2.y, acc[2 * i + 1]);
        }
    }
    dsum += __shfl_xor(dsum, 1);
    dsum += __shfl_xor(dsum, 2);
    dsum += __shfl_xor(dsum, 16);
    dsum += __shfl_xor(dsum, 32);
#pragma unroll
    for (int i = 0; i < 8; ++i) {
        acc[i] += __shfl_xor(acc[i], 16);
        acc[i] += __shfl_xor(acc[i], 32);
    }
    const float inv = 4.0f / dsum;   // each (edge,head) counted by 4 lanes
    if (es == 0) {
        union { ushort u8[8]; uint4 u; } pk;
#pragma unroll
        for (int i = 0; i < 8; ++i) {
            float v = fmaxf(fmaf(acc[i], inv, bias[f8 + i]), 0.f);
            pk.u8[i] = f2bf_bits(v);
        }
        *(uint4*)&out[(size_t)n * FH + f8] = pk.u;
    }
}

// ---------------------------------------------------------------------------
// Mean pool + final linear fused. X rows single-use -> nontemporal.
// ---------------------------------------------------------------------------
__global__ __launch_bounds__(256) void pool_final_kernel(
    const __hip_bfloat16* __restrict__ X, const int* __restrict__ batch,
    const float* __restrict__ wl, const float* __restrict__ bl,
    float* __restrict__ out)
{
    const int g = blockIdx.x;
    const int t = threadIdx.x;
    int a = 0, b = NN;
    while (a < b) { int m = (a + b) >> 1; if (batch[m] < g) a = m + 1; else b = m; }
    const int gs = a;
    b = NN;
    while (a < b) { int m = (a + b) >> 1; if (batch[m] <= g) a = m + 1; else b = m; }
    const int ge = a;

    const int rg = t >> 4;
    const int l16 = t & 15;
    float acc[8];
#pragma unroll
    for (int i = 0; i < 8; ++i) acc[i] = 0.f;
    for (int r = gs + rg; r < ge; r += 16) {
        union { uint4x u; __hip_bfloat162 bb[4]; } cv;
        cv.u = __builtin_nontemporal_load((const uint4x*)&X[(size_t)r * FH + l16 * 8]);
#pragma unroll
        for (int i = 0; i < 4; ++i) {
            float2 f = __bfloat1622float2(cv.bb[i]);
            acc[2 * i]     += f.x;
            acc[2 * i + 1] += f.y;
        }
    }
    __shared__ float red[16][128];
    __shared__ float pl[128];
#pragma unroll
    for (int i = 0; i < 8; ++i) red[rg][l16 * 8 + i] = acc[i];
    __syncthreads();
    if (t < 128) {
        float s = 0.f;
#pragma unroll
        for (int j = 0; j < 16; ++j) s += red[j][t];
        pl[t] = s;
    }
    __syncthreads();
    if (t < OC) {
        float invc = 1.0f / fmaxf((float)(ge - gs), 1.0f);
        float a2 = 0.f;
        for (int k = 0; k < FH; ++k)
            a2 = fmaf(pl[k], wl[k * OC + t], a2);
        out[g * OC + t] = a2 * invc + bl[t];
    }
}

// ---------------------------------------------------------------------------
extern "C" void kernel_launch(void* const* d_in, const int* in_sizes, int n_in,
                              void* d_out, int out_size, void* d_ws, size_t ws_size,
                              hipStream_t stream) {
    const float* x       = (const float*)d_in[0];
    const int*   ei      = (const int*)d_in[1];   // [2, NE]
    const int*   batch   = (const int*)d_in[2];
    const float* W1      = (const float*)d_in[3];
    const float* as1     = (const float*)d_in[4];
    const float* ad1     = (const float*)d_in[5];
    const float* b1      = (const float*)d_in[6];
    const float* W2      = (const float*)d_in[7];
    const float* as2     = (const float*)d_in[8];
    const float* ad2     = (const float*)d_in[9];
    const float* b2      = (const float*)d_in[10];
    const float* wlin    = (const float*)d_in[11];
    const float* blin    = (const float*)d_in[12];
    float* out = (float*)d_out;

    // workspace layout (everything fully rewritten each call -> no memset)
    __hip_bfloat16* hbuf = (__hip_bfloat16*)d_ws;        // NN*FH bf16 (gemm out)
    __hip_bfloat16* abuf = hbuf + (size_t)NN * FH;       // NN*FH bf16 (agg out)
    float* asrc  = (float*)(abuf + (size_t)NN * FH);     // NN*4
    float* adst  = asrc + (size_t)NN * NHEAD;            // NN*4
    int* offs    = (int*)(adst + (size_t)NN * NHEAD);    // NN+1
    int* csrc    = offs + NN + 1;                        // ET
    int2* ebuf   = (int2*)(((uintptr_t)(csrc + ET) + 7) & ~(uintptr_t)7); // NE int2
    int* bh      = (int*)(ebuf + NE);         // NBK*HBLK
    int* ebase   = bh + NBK * HBLK;           // NBK+1
    ushort* wt   = (ushort*)(((uintptr_t)(ebase + NBK + 1) + 15) & ~(uintptr_t)15); // 2*WPLANE

    // 1. Fused: layer-1 GEMM (in-kernel W1 pack) + bucket hist + W2 pack
    fused_gemm_hist_kernel<<<GEMM1_GRID + HBLK, 1024, 0, stream>>>(
        ei, bh, x, W1, W2, wt, as1, ad1, hbuf, asrc, adst);

    // 2-3. CSR build (scan folded into scatter; block 0 publishes ebase/offs[NN])
    bucket_scatter_kernel<<<HBLK, 1024, 0, stream>>>(ei, bh, ebase, offs, ebuf);
    bucket_csr_kernel<<<NBK, 1024, 0, stream>>>(ebuf, ebase, offs, csrc);

    const int agg_grid = NN / 4;

    // 4. Layer 1 aggregation
    gat_agg_kernel<<<agg_grid, 256, 0, stream>>>(hbuf, asrc, adst, offs, csrc, b1, abuf);
    // 5. Layer 2 GEMM (1024-thr / 256-row blocks)
    gemm_att_bf16_kernel<<<GEMM2_GRID, 1024, 0, stream>>>(abuf, wt, as2, ad2, hbuf, asrc, adst);
    // 6. Layer 2 aggregation
    gat_agg_kernel<<<agg_grid, 256, 0, stream>>>(hbuf, asrc, adst, offs, csrc, b2, abuf);

    // 7. Pool + final linear (fused)
    pool_final_kernel<<<NG, 256, 0, stream>>>(abuf, batch, wlin, blin, out);
}